// Round 5
// baseline (639.642 us; speedup 1.0000x reference)
//
#include <hip/hip_runtime.h>
#include <hip/hip_bf16.h>

#define N_NODES 50000
#define N_EDGES 800000
#define IN_F 512
#define HID 256
#define HEADS 8
#define DHEAD 32
#define N_CLS 40
#define NCLS_PAD 64

typedef __bf16 bf16x8 __attribute__((ext_vector_type(8)));
typedef float f32x4 __attribute__((ext_vector_type(4)));

// f32 att/bias workspace layout (in floats)
#define AT_AL0 0
#define AT_AR0 256
#define AT_AL1 512
#define AT_AR1 768
#define AT_AL2 1024
#define AT_AR2 1088
#define AT_B0  1152
#define AT_B1  1408
#define AT_B2  1664
#define AT_SZ  1792

__device__ __forceinline__ float ldflag(const void* p, long long i, int isbf) {
  return isbf ? __bfloat162float(((const __hip_bfloat16*)p)[i])
              : ((const float*)p)[i];
}
// unpack a packed bf16 pair (u32): low-address element in low 16 bits
__device__ __forceinline__ float blo(unsigned u) { return __uint_as_float(u << 16); }
__device__ __forceinline__ float bhi(unsigned u) { return __uint_as_float(u & 0xffff0000u); }
// pack two floats -> bf16 pair in u32
__device__ __forceinline__ unsigned pk2(float a, float b) {
  unsigned x = __bfloat16_as_ushort(__float2bfloat16(a));
  unsigned y = __bfloat16_as_ushort(__float2bfloat16(b));
  return x | (y << 16);
}

// ---------------- dtype detect + constant prep (merged, 1 block) ----------------
__global__ void k_detect_prep(const unsigned short* __restrict__ raw, int* __restrict__ flag,
                              const void* al0, const void* ar0, const void* al1, const void* ar1,
                              const void* al2, const void* ar2, const void* b0, const void* b1,
                              const void* b2, float* __restrict__ att) {
  __shared__ int cnt[256];
  int t = threadIdx.x;
  int c = 0;
  for (int i = t; i < 8192; i += 256) {
    int e = (raw[i] >> 7) & 0xFF;
    if (e >= 0x90) c++;
  }
  cnt[t] = c;
  __syncthreads();
  for (int s = 128; s; s >>= 1) {
    if (t < s) cnt[t] += cnt[t + s];
    __syncthreads();
  }
  __shared__ int sflag;
  if (t == 0) { sflag = (cnt[0] > 64) ? 0 : 1; *flag = sflag; }
  __syncthreads();
  int isbf = sflag;
  att[AT_AL0 + t] = ldflag(al0, t, isbf);
  att[AT_AR0 + t] = ldflag(ar0, t, isbf);
  att[AT_AL1 + t] = ldflag(al1, t, isbf);
  att[AT_AR1 + t] = ldflag(ar1, t, isbf);
  att[AT_B0 + t]  = ldflag(b0, t, isbf);
  att[AT_B1 + t]  = ldflag(b1, t, isbf);
  if (t < N_CLS) {
    att[AT_AL2 + t] = ldflag(al2, t, isbf);
    att[AT_AR2 + t] = ldflag(ar2, t, isbf);
    att[AT_B2 + t]  = ldflag(b2, t, isbf);
  }
}

// ---------------- CSR build (by dst) ----------------
__global__ void k_hist(const int* __restrict__ dst, int* __restrict__ cnt) {
  int e = blockIdx.x * blockDim.x + threadIdx.x;
  if (e < N_EDGES) atomicAdd(&cnt[dst[e]], 1);
}

#define SCAN_B 512
#define SCAN_NB ((N_NODES + SCAN_B - 1) / SCAN_B)   // 98

__global__ __launch_bounds__(SCAN_B) void k_scan_blocks(const int* __restrict__ deg,
                                                        int* __restrict__ excl,
                                                        int* __restrict__ partial) {
  __shared__ int buf[SCAN_B];
  int t = threadIdx.x;
  int i = blockIdx.x * SCAN_B + t;
  int v = (i < N_NODES) ? deg[i] : 0;
  buf[t] = v;
  __syncthreads();
  for (int off = 1; off < SCAN_B; off <<= 1) {
    int x = (t >= off) ? buf[t - off] : 0;
    __syncthreads();
    buf[t] += x;
    __syncthreads();
  }
  if (i < N_NODES) excl[i] = buf[t] - v;
  if (t == SCAN_B - 1) partial[blockIdx.x] = buf[t];
}

__global__ void k_scan_partials(int* __restrict__ partial, int* __restrict__ rowptr) {
  __shared__ int buf[SCAN_NB];
  int t = threadIdx.x;
  if (t < SCAN_NB) buf[t] = partial[t];
  __syncthreads();
  if (t == 0) {
    int run = 0;
    for (int b = 0; b < SCAN_NB; b++) { int v = buf[b]; buf[b] = run; run += v; }
    rowptr[N_NODES] = run;
  }
  __syncthreads();
  if (t < SCAN_NB) partial[t] = buf[t];
}

__global__ void k_scan_add(int* __restrict__ rowptr, const int* __restrict__ partial) {
  int i = blockIdx.x * blockDim.x + threadIdx.x;
  if (i < N_NODES) rowptr[i] += partial[i / SCAN_B];
}

__global__ void k_scatter(const int* __restrict__ src, const int* __restrict__ dst,
                          const int* __restrict__ rowptr, int* __restrict__ cursor,
                          int* __restrict__ csr_src) {
  int e = blockIdx.x * blockDim.x + threadIdx.x;
  if (e < N_EDGES) {
    int d = dst[e];
    int pos = rowptr[d] + atomicAdd(&cursor[d], 1);
    csr_src[pos] = src[e];
  }
}

// ---------------- weight transpose (+ N padding) -> bf16 [Ndst][K] ----------------
__global__ void k_transpose16(const void* __restrict__ W, __hip_bfloat16* __restrict__ Wt,
                              int K, int Nsrc, int Ndst, const int* __restrict__ flag) {
  int isbf = *flag;
  int i = blockIdx.x * blockDim.x + threadIdx.x;
  if (i >= Ndst * K) return;
  int n = i / K, k = i - n * K;
  float v = 0.f;
  if (n < Nsrc) v = ldflag(W, (long long)k * Nsrc + n, isbf);
  Wt[(size_t)n * K + k] = __float2bfloat16(v);
}

// ---------------- MFMA GEMM, 64 rows x (NT*64) cols per block ----------------
// C[M][NC] = A[M][K] * Bt[NC][K]^T. A dtype: bf16 if (force_bf || *flag), else f32
// (cast fused into staging). A is read exactly once; Bt (<=262 KB) stays L2-resident.
// 4 waves: wave w owns cols w*(NT*16) .. +NT*16-1, all 64 rows (4 m-tiles x NT n-tiles).
template<int NT>
__global__ __launch_bounds__(256) void k_gemm_fused(const void* __restrict__ A,
                                                    const __hip_bfloat16* __restrict__ Bt,
                                                    __hip_bfloat16* __restrict__ C,
                                                    int M, int K,
                                                    const int* __restrict__ flag, int force_bf) {
  constexpr int NC = NT * 64;
  __shared__ unsigned short As[64][40];
  __shared__ unsigned short Bs[NC][40];
  const int isbf = force_bf ? 1 : *flag;
  int tid = threadIdx.x;
  int m0 = blockIdx.x * 64;
  int lrow = tid >> 2;          // 0..63
  int lcol = (tid & 3) * 8;     // 0,8,16,24
  int wave = tid >> 6, lane = tid & 63;
  int wn = wave * (NT * 16);
  int lm = lane & 15, quad = lane >> 4;

  f32x4 acc[4][NT] = {};
  for (int k0 = 0; k0 < K; k0 += 32) {
    int ga = m0 + lrow;
    uint4 av = make_uint4(0u, 0u, 0u, 0u);
    if (isbf) {
      if (ga < M) av = *(const uint4*)((const __hip_bfloat16*)A + (size_t)ga * K + k0 + lcol);
    } else {
      if (ga < M) {
        const float* ap = (const float*)A + (size_t)ga * K + k0 + lcol;
        float4 f1 = *(const float4*)ap;
        float4 f2 = *(const float4*)(ap + 4);
        av.x = pk2(f1.x, f1.y); av.y = pk2(f1.z, f1.w);
        av.z = pk2(f2.x, f2.y); av.w = pk2(f2.z, f2.w);
      }
    }
    uint4 bv[NT];
    #pragma unroll
    for (int j = 0; j < NT; j++)
      bv[j] = *(const uint4*)(Bt + (size_t)(lrow + 64 * j) * K + k0 + lcol);
    __syncthreads();            // previous iteration's LDS reads done
    *(uint4*)(&As[lrow][lcol]) = av;
    #pragma unroll
    for (int j = 0; j < NT; j++)
      *(uint4*)(&Bs[lrow + 64 * j][lcol]) = bv[j];
    __syncthreads();
    bf16x8 af[4], bfr[NT];
    #pragma unroll
    for (int mi = 0; mi < 4; mi++)
      af[mi] = *(const bf16x8*)(&As[mi * 16 + lm][quad * 8]);
    #pragma unroll
    for (int ni = 0; ni < NT; ni++)
      bfr[ni] = *(const bf16x8*)(&Bs[wn + ni * 16 + lm][quad * 8]);
    #pragma unroll
    for (int mi = 0; mi < 4; mi++)
      #pragma unroll
      for (int ni = 0; ni < NT; ni++)
        acc[mi][ni] = __builtin_amdgcn_mfma_f32_16x16x32_bf16(af[mi], bfr[ni], acc[mi][ni], 0, 0, 0);
  }
  // C/D layout: col = lane&15, row = quad*4 + r  (m89/m91 verified)
  #pragma unroll
  for (int mi = 0; mi < 4; mi++)
    #pragma unroll
    for (int ni = 0; ni < NT; ni++)
      #pragma unroll
      for (int r = 0; r < 4; r++) {
        int gm = m0 + mi * 16 + quad * 4 + r;
        int gn = wn + ni * 16 + lm;
        if (gm < M) C[(size_t)gm * NC + gn] = __float2bfloat16(acc[mi][ni][r]);
      }
}

// ---------------- el/er for HID=256/HEADS=8 layers: vectorized 16B/lane ----------------
__global__ void k_eler8(const uint4* __restrict__ feat_rows,   // [N][32] uint4
                        const float* __restrict__ al, const float* __restrict__ ar,
                        float* __restrict__ el, float* __restrict__ er) {
  int i = blockIdx.x * blockDim.x + threadIdx.x;   // (n,h)
  if (i >= N_NODES * HEADS) return;
  int n = i >> 3, h = i & 7;
  const uint4* base = feat_rows + (size_t)n * 32 + h * 4;
  const float* alh = al + h * DHEAD;
  const float* arh = ar + h * DHEAD;
  float sl = 0.f, sr = 0.f;
  #pragma unroll
  for (int q = 0; q < 4; q++) {
    uint4 v = base[q];
    unsigned u[4] = {v.x, v.y, v.z, v.w};
    #pragma unroll
    for (int w = 0; w < 4; w++) {
      int d = q * 8 + w * 2;
      float f0 = blo(u[w]), f1 = bhi(u[w]);
      sl += f0 * alh[d] + f1 * alh[d + 1];
      sr += f0 * arh[d] + f1 * arh[d + 1];
    }
  }
  el[i] = sl;
  er[i] = sr;
}

// ---------------- el/er for layer 2 (1 head, 40 dims, stride 64) ----------------
__global__ void k_eler2(const __hip_bfloat16* __restrict__ feat2,
                        const float* __restrict__ al, const float* __restrict__ ar,
                        float* __restrict__ el, float* __restrict__ er) {
  int n = blockIdx.x * blockDim.x + threadIdx.x;
  if (n >= N_NODES) return;
  const __hip_bfloat16* f = feat2 + (size_t)n * NCLS_PAD;
  float sl = 0.f, sr = 0.f;
  for (int d = 0; d < N_CLS; d++) {
    float v = __bfloat162float(f[d]);
    sl += v * al[d];
    sr += v * ar[d];
  }
  el[n] = sl;
  er[n] = sr;
}

// ---------------- fused edge-softmax + aggregation, 8 slots x 32 lanes ----------------
// lane owns 8 channels (uint4/edge). No max-subtraction (shift-invariant, exp clamped).
// Unroll-2: two independent csr->el/feat gather chains in flight (latency-bound fix).
__global__ __launch_bounds__(256) void k_aggregate8(const int* __restrict__ rowptr,
                                                    const int* __restrict__ csr_src,
                                                    const uint4* __restrict__ feat_rows,
                                                    const float* __restrict__ el,
                                                    const float* __restrict__ er,
                                                    const float* __restrict__ bias,
                                                    __hip_bfloat16* __restrict__ out) {
  __shared__ float lds_acc[8][256];
  __shared__ float lds_l[8][32];
  int n = blockIdx.x;
  int t = threadIdx.x;
  int slot = t >> 5;      // 0..7
  int c = t & 31;         // channel group: channels c*8..c*8+7
  int hh = c >> 2;        // head of this group
  float er_n = er[n * HEADS + hh];
  int beg = rowptr[n], end = rowptr[n + 1];
  float l = 0.f;
  float acc[8] = {0.f, 0.f, 0.f, 0.f, 0.f, 0.f, 0.f, 0.f};
  int i = beg + slot;
  for (; i + 8 < end; i += 16) {
    int s1 = csr_src[i];
    int s2 = csr_src[i + 8];
    float el1 = el[s1 * HEADS + hh];
    float el2 = el[s2 * HEADS + hh];
    uint4 f1 = feat_rows[(size_t)s1 * 32 + c];
    uint4 f2 = feat_rows[(size_t)s2 * 32 + c];
    float x1 = el1 + er_n, x2 = el2 + er_n;
    float e1 = x1 > 0.f ? x1 : 0.2f * x1;
    float e2 = x2 > 0.f ? x2 : 0.2f * x2;
    float p1 = __expf(fminf(e1, 60.f));
    float p2 = __expf(fminf(e2, 60.f));
    l += p1 + p2;
    acc[0] += p1 * blo(f1.x) + p2 * blo(f2.x); acc[1] += p1 * bhi(f1.x) + p2 * bhi(f2.x);
    acc[2] += p1 * blo(f1.y) + p2 * blo(f2.y); acc[3] += p1 * bhi(f1.y) + p2 * bhi(f2.y);
    acc[4] += p1 * blo(f1.z) + p2 * blo(f2.z); acc[5] += p1 * bhi(f1.z) + p2 * bhi(f2.z);
    acc[6] += p1 * blo(f1.w) + p2 * blo(f2.w); acc[7] += p1 * bhi(f1.w) + p2 * bhi(f2.w);
  }
  if (i < end) {
    int s = csr_src[i];
    float elv = el[s * HEADS + hh];
    uint4 fv = feat_rows[(size_t)s * 32 + c];
    float x = elv + er_n;
    float e = x > 0.f ? x : 0.2f * x;
    float p = __expf(fminf(e, 60.f));
    l += p;
    acc[0] += p * blo(fv.x); acc[1] += p * bhi(fv.x);
    acc[2] += p * blo(fv.y); acc[3] += p * bhi(fv.y);
    acc[4] += p * blo(fv.z); acc[5] += p * bhi(fv.z);
    acc[6] += p * blo(fv.w); acc[7] += p * bhi(fv.w);
  }
  *(float4*)&lds_acc[slot][c * 8]     = make_float4(acc[0], acc[1], acc[2], acc[3]);
  *(float4*)&lds_acc[slot][c * 8 + 4] = make_float4(acc[4], acc[5], acc[6], acc[7]);
  lds_l[slot][c] = l;
  __syncthreads();
  float a = 0.f, L = 0.f;
  #pragma unroll
  for (int s2 = 0; s2 < 8; s2++) { a += lds_acc[s2][t]; L += lds_l[s2][t >> 3]; }
  float o = a / fmaxf(L, 1e-9f) + bias[t];
  o = fmaxf(o, 0.f);                            // ReLU (layers 0,1)
  out[(size_t)n * HID + t] = __float2bfloat16(o);
}

// ---------------- layer 2 aggregate: 32 slots x 8 lanes (64-ch padded rows) ----------------
__global__ __launch_bounds__(256) void k_aggregate1(const int* __restrict__ rowptr,
                                                    const int* __restrict__ csr_src,
                                                    const uint4* __restrict__ fr2,  // [N][8] uint4
                                                    const float* __restrict__ el,
                                                    const float* __restrict__ er,
                                                    const float* __restrict__ bias,
                                                    void* __restrict__ out,
                                                    const int* __restrict__ flag) {
  __shared__ float lds_acc[32][64];
  __shared__ float lds_l[32][8];
  int isbf = *flag;
  int n = blockIdx.x;
  int t = threadIdx.x;
  int slot = t >> 3;      // 0..31
  int c = t & 7;
  float er_n = er[n];
  int beg = rowptr[n], end = rowptr[n + 1];
  float l = 0.f;
  float acc[8] = {0.f, 0.f, 0.f, 0.f, 0.f, 0.f, 0.f, 0.f};
  int i = beg + slot;
  for (; i + 32 < end; i += 64) {
    int s1 = csr_src[i], s2 = csr_src[i + 32];
    float el1 = el[s1], el2 = el[s2];
    uint4 f1 = fr2[(size_t)s1 * 8 + c];
    uint4 f2 = fr2[(size_t)s2 * 8 + c];
    float x1 = el1 + er_n, x2 = el2 + er_n;
    float e1 = x1 > 0.f ? x1 : 0.2f * x1;
    float e2 = x2 > 0.f ? x2 : 0.2f * x2;
    float p1 = __expf(fminf(e1, 60.f));
    float p2 = __expf(fminf(e2, 60.f));
    l += p1 + p2;
    acc[0] += p1 * blo(f1.x) + p2 * blo(f2.x); acc[1] += p1 * bhi(f1.x) + p2 * bhi(f2.x);
    acc[2] += p1 * blo(f1.y) + p2 * blo(f2.y); acc[3] += p1 * bhi(f1.y) + p2 * bhi(f2.y);
    acc[4] += p1 * blo(f1.z) + p2 * blo(f2.z); acc[5] += p1 * bhi(f1.z) + p2 * bhi(f2.z);
    acc[6] += p1 * blo(f1.w) + p2 * blo(f2.w); acc[7] += p1 * bhi(f1.w) + p2 * bhi(f2.w);
  }
  if (i < end) {
    int s = csr_src[i];
    float x = el[s] + er_n;
    uint4 fv = fr2[(size_t)s * 8 + c];
    float e = x > 0.f ? x : 0.2f * x;
    float p = __expf(fminf(e, 60.f));
    l += p;
    acc[0] += p * blo(fv.x); acc[1] += p * bhi(fv.x);
    acc[2] += p * blo(fv.y); acc[3] += p * bhi(fv.y);
    acc[4] += p * blo(fv.z); acc[5] += p * bhi(fv.z);
    acc[6] += p * blo(fv.w); acc[7] += p * bhi(fv.w);
  }
  *(float4*)&lds_acc[slot][c * 8]     = make_float4(acc[0], acc[1], acc[2], acc[3]);
  *(float4*)&lds_acc[slot][c * 8 + 4] = make_float4(acc[4], acc[5], acc[6], acc[7]);
  lds_l[slot][c] = l;
  __syncthreads();
  if (t < N_CLS) {
    float a = 0.f, L = 0.f;
    #pragma unroll
    for (int s2 = 0; s2 < 32; s2++) { a += lds_acc[s2][t]; L += lds_l[s2][t >> 3]; }
    float o = a / fmaxf(L, 1e-9f) + bias[t];    // no ReLU on output layer
    if (isbf) ((__hip_bfloat16*)out)[(size_t)n * N_CLS + t] = __float2bfloat16(o);
    else      ((float*)out)[(size_t)n * N_CLS + t] = o;
  }
}

// ---------------- launch ----------------
static inline size_t align_up(size_t x) { return (x + 255) & ~(size_t)255; }

extern "C" void kernel_launch(void* const* d_in, const int* in_sizes, int n_in,
                              void* d_out, int out_size, void* d_ws, size_t ws_size,
                              hipStream_t stream) {
  const void* in_feat = d_in[0];
  const int* src = (const int*)d_in[1];
  const int* dst = (const int*)d_in[2];
  const void* W0  = d_in[3];
  const void* al0 = d_in[4];
  const void* ar0 = d_in[5];
  const void* b0  = d_in[6];
  const void* W1  = d_in[7];
  const void* al1 = d_in[8];
  const void* ar1 = d_in[9];
  const void* b1  = d_in[10];
  const void* W2  = d_in[11];
  const void* al2 = d_in[12];
  const void* ar2 = d_in[13];
  const void* b2  = d_in[14];

  char* p = (char*)d_ws;
  int* flag = (int*)p;                   p += 256;
  float* att = (float*)p;                p += align_up(AT_SZ * sizeof(float));
  int* rowptr = (int*)p;                 p += align_up((N_NODES + 1) * sizeof(int));
  int* cursor = (int*)p;                 p += align_up(N_NODES * sizeof(int));
  int* csr_src = (int*)p;                p += align_up(N_EDGES * sizeof(int));
  int* partial = (int*)p;                p += align_up(SCAN_NB * sizeof(int));
  __hip_bfloat16* feat16 = (__hip_bfloat16*)p; p += align_up((size_t)N_NODES * HID * sizeof(__hip_bfloat16));
  __hip_bfloat16* h16 = (__hip_bfloat16*)p;    p += align_up((size_t)N_NODES * HID * sizeof(__hip_bfloat16));
  float* el = (float*)p;                 p += align_up((size_t)N_NODES * HEADS * sizeof(float));
  float* er = (float*)p;                 p += align_up((size_t)N_NODES * HEADS * sizeof(float));
  __hip_bfloat16* w0t = (__hip_bfloat16*)p;    p += align_up((size_t)HID * IN_F * sizeof(__hip_bfloat16));
  __hip_bfloat16* w1t = (__hip_bfloat16*)p;    p += align_up((size_t)HID * HID * sizeof(__hip_bfloat16));
  __hip_bfloat16* w2t = (__hip_bfloat16*)p;    p += align_up((size_t)NCLS_PAD * HID * sizeof(__hip_bfloat16));

  const int EB = (N_EDGES + 255) / 256;
  const int MB64 = (N_NODES + 63) / 64;

  // ---- dtype detection + constant prep ----
  k_detect_prep<<<1, 256, 0, stream>>>((const unsigned short*)in_feat, flag,
                                       al0, ar0, al1, ar1, al2, ar2, b0, b1, b2, att);

  // ---- CSR build ----
  hipMemsetAsync(cursor, 0, N_NODES * sizeof(int), stream);
  k_hist<<<EB, 256, 0, stream>>>(dst, cursor);
  k_scan_blocks<<<SCAN_NB, SCAN_B, 0, stream>>>(cursor, rowptr, partial);
  k_scan_partials<<<1, 128, 0, stream>>>(partial, rowptr);
  k_scan_add<<<(N_NODES + 255) / 256, 256, 0, stream>>>(rowptr, partial);
  hipMemsetAsync(cursor, 0, N_NODES * sizeof(int), stream);
  k_scatter<<<EB, 256, 0, stream>>>(src, dst, rowptr, cursor, csr_src);

  // ---- weight transposes (-> bf16 [N][K]) ----
  k_transpose16<<<(HID * IN_F + 255) / 256, 256, 0, stream>>>(W0, w0t, IN_F, HID, HID, flag);
  k_transpose16<<<(HID * HID + 255) / 256, 256, 0, stream>>>(W1, w1t, HID, HID, HID, flag);
  k_transpose16<<<(NCLS_PAD * HID + 255) / 256, 256, 0, stream>>>(W2, w2t, HID, N_CLS, NCLS_PAD, flag);

  // ---- layer 0 (cast fused into GEMM staging) ----
  k_gemm_fused<4><<<MB64, 256, 0, stream>>>(in_feat, w0t, feat16, N_NODES, IN_F, flag, 0);
  k_eler8<<<(N_NODES * HEADS + 255) / 256, 256, 0, stream>>>((const uint4*)feat16, att + AT_AL0, att + AT_AR0, el, er);
  k_aggregate8<<<N_NODES, 256, 0, stream>>>(rowptr, csr_src, (const uint4*)feat16, el, er, att + AT_B0, h16);

  // ---- layer 1 ----
  k_gemm_fused<4><<<MB64, 256, 0, stream>>>(h16, w1t, feat16, N_NODES, HID, flag, 1);
  k_eler8<<<(N_NODES * HEADS + 255) / 256, 256, 0, stream>>>((const uint4*)feat16, att + AT_AL1, att + AT_AR1, el, er);
  k_aggregate8<<<N_NODES, 256, 0, stream>>>(rowptr, csr_src, (const uint4*)feat16, el, er, att + AT_B1, h16);

  // ---- layer 2 (feat16 reused as [N][64] padded feat2) ----
  k_gemm_fused<1><<<MB64, 256, 0, stream>>>(h16, w2t, feat16, N_NODES, HID, flag, 1);
  k_eler2<<<(N_NODES + 255) / 256, 256, 0, stream>>>(feat16, att + AT_AL2, att + AT_AR2, el, er);
  k_aggregate1<<<N_NODES, 256, 0, stream>>>(rowptr, csr_src, (const uint4*)feat16, el, er, att + AT_B2, d_out, flag);
}

// Round 6
// 570.537 us; speedup vs baseline: 1.1211x; 1.1211x over previous
//
#include <hip/hip_runtime.h>
#include <hip/hip_bf16.h>

#define N_NODES 50000
#define N_EDGES 800000
#define IN_F 512
#define HID 256
#define HEADS 8
#define DHEAD 32
#define N_CLS 40
#define NCLS_PAD 64

typedef __bf16 bf16x8 __attribute__((ext_vector_type(8)));
typedef float f32x4 __attribute__((ext_vector_type(4)));

// f32 att/bias workspace layout (in floats)
#define AT_AL0 0
#define AT_AR0 256
#define AT_AL1 512
#define AT_AR1 768
#define AT_AL2 1024
#define AT_AR2 1088
#define AT_B0  1152
#define AT_B1  1408
#define AT_B2  1664
#define AT_SZ  1792

__device__ __forceinline__ float ldflag(const void* p, long long i, int isbf) {
  return isbf ? __bfloat162float(((const __hip_bfloat16*)p)[i])
              : ((const float*)p)[i];
}
// unpack a packed bf16 pair (u32): low-address element in low 16 bits
__device__ __forceinline__ float blo(unsigned u) { return __uint_as_float(u << 16); }
__device__ __forceinline__ float bhi(unsigned u) { return __uint_as_float(u & 0xffff0000u); }
// pack two floats -> bf16 pair in u32
__device__ __forceinline__ unsigned pk2(float a, float b) {
  unsigned x = __bfloat16_as_ushort(__float2bfloat16(a));
  unsigned y = __bfloat16_as_ushort(__float2bfloat16(b));
  return x | (y << 16);
}

// ---------------- dtype detect + constant prep (merged, 1 block) ----------------
__global__ void k_detect_prep(const unsigned short* __restrict__ raw, int* __restrict__ flag,
                              const void* al0, const void* ar0, const void* al1, const void* ar1,
                              const void* al2, const void* ar2, const void* b0, const void* b1,
                              const void* b2, float* __restrict__ att) {
  __shared__ int cnt[256];
  int t = threadIdx.x;
  int c = 0;
  for (int i = t; i < 8192; i += 256) {
    int e = (raw[i] >> 7) & 0xFF;
    if (e >= 0x90) c++;
  }
  cnt[t] = c;
  __syncthreads();
  for (int s = 128; s; s >>= 1) {
    if (t < s) cnt[t] += cnt[t + s];
    __syncthreads();
  }
  __shared__ int sflag;
  if (t == 0) { sflag = (cnt[0] > 64) ? 0 : 1; *flag = sflag; }
  __syncthreads();
  int isbf = sflag;
  att[AT_AL0 + t] = ldflag(al0, t, isbf);
  att[AT_AR0 + t] = ldflag(ar0, t, isbf);
  att[AT_AL1 + t] = ldflag(al1, t, isbf);
  att[AT_AR1 + t] = ldflag(ar1, t, isbf);
  att[AT_B0 + t]  = ldflag(b0, t, isbf);
  att[AT_B1 + t]  = ldflag(b1, t, isbf);
  if (t < N_CLS) {
    att[AT_AL2 + t] = ldflag(al2, t, isbf);
    att[AT_AR2 + t] = ldflag(ar2, t, isbf);
    att[AT_B2 + t]  = ldflag(b2, t, isbf);
  }
}

// ---------------- CSR build (by dst) ----------------
__global__ void k_hist(const int* __restrict__ dst, int* __restrict__ cnt) {
  int e = blockIdx.x * blockDim.x + threadIdx.x;
  if (e < N_EDGES) atomicAdd(&cnt[dst[e]], 1);
}

#define SCAN_B 512
#define SCAN_NB ((N_NODES + SCAN_B - 1) / SCAN_B)   // 98

__global__ __launch_bounds__(SCAN_B) void k_scan_blocks(const int* __restrict__ deg,
                                                        int* __restrict__ excl,
                                                        int* __restrict__ partial) {
  __shared__ int buf[SCAN_B];
  int t = threadIdx.x;
  int i = blockIdx.x * SCAN_B + t;
  int v = (i < N_NODES) ? deg[i] : 0;
  buf[t] = v;
  __syncthreads();
  for (int off = 1; off < SCAN_B; off <<= 1) {
    int x = (t >= off) ? buf[t - off] : 0;
    __syncthreads();
    buf[t] += x;
    __syncthreads();
  }
  if (i < N_NODES) excl[i] = buf[t] - v;
  if (t == SCAN_B - 1) partial[blockIdx.x] = buf[t];
}

__global__ void k_scan_partials(int* __restrict__ partial, int* __restrict__ rowptr) {
  __shared__ int buf[SCAN_NB];
  int t = threadIdx.x;
  if (t < SCAN_NB) buf[t] = partial[t];
  __syncthreads();
  if (t == 0) {
    int run = 0;
    for (int b = 0; b < SCAN_NB; b++) { int v = buf[b]; buf[b] = run; run += v; }
    rowptr[N_NODES] = run;
  }
  __syncthreads();
  if (t < SCAN_NB) partial[t] = buf[t];
}

__global__ void k_scan_add(int* __restrict__ rowptr, const int* __restrict__ partial) {
  int i = blockIdx.x * blockDim.x + threadIdx.x;
  if (i < N_NODES) rowptr[i] += partial[i / SCAN_B];
}

__global__ void k_scatter(const int* __restrict__ src, const int* __restrict__ dst,
                          const int* __restrict__ rowptr, int* __restrict__ cursor,
                          int* __restrict__ csr_src) {
  int e = blockIdx.x * blockDim.x + threadIdx.x;
  if (e < N_EDGES) {
    int d = dst[e];
    int pos = rowptr[d] + atomicAdd(&cursor[d], 1);
    csr_src[pos] = src[e];
  }
}

// ---------------- weight transpose (+ N padding) -> bf16 [Ndst][K] ----------------
__global__ void k_transpose16(const void* __restrict__ W, __hip_bfloat16* __restrict__ Wt,
                              int K, int Nsrc, int Ndst, const int* __restrict__ flag) {
  int isbf = *flag;
  int i = blockIdx.x * blockDim.x + threadIdx.x;
  if (i >= Ndst * K) return;
  int n = i / K, k = i - n * K;
  float v = 0.f;
  if (n < Nsrc) v = ldflag(W, (long long)k * Nsrc + n, isbf);
  Wt[(size_t)n * K + k] = __float2bfloat16(v);
}

// ---------------- MFMA bf16 GEMM, 64x64 tile (round-4 structure), dual-dtype A ----------------
// C[M][N] = A[M][K] * Bt[N][K]^T. A is bf16 if (force_bf || *flag) else f32 (cast fused
// into staging). grid (M/64, N/64) = 3128 blocks for N=256: oversubscription hides latency
// (round-5 lesson: 782 wide-N blocks -> 23% occupancy, MfmaUtil 4%).
__global__ __launch_bounds__(256) void k_gemm64(const void* __restrict__ A,
                                                const __hip_bfloat16* __restrict__ Bt,
                                                __hip_bfloat16* __restrict__ C,
                                                int M, int K, int N,
                                                const int* __restrict__ flag, int force_bf) {
  __shared__ unsigned short As[64][40];  // 80 B pitch: 16B-aligned rows, spreads banks
  __shared__ unsigned short Bs[64][40];
  const int isbf = force_bf ? 1 : *flag;
  int tid = threadIdx.x;
  int m0 = blockIdx.x * 64, n0 = blockIdx.y * 64;
  int lrow = tid >> 2;          // 0..63
  int lcol = (tid & 3) * 8;     // 0,8,16,24
  int wave = tid >> 6, lane = tid & 63;
  int wm = (wave >> 1) * 32, wn = (wave & 1) * 32;
  int lm = lane & 15, quad = lane >> 4;
  f32x4 acc[2][2] = {};
  for (int k0 = 0; k0 < K; k0 += 32) {
    int ga = m0 + lrow;
    uint4 av = make_uint4(0u, 0u, 0u, 0u);
    if (isbf) {
      if (ga < M) av = *(const uint4*)((const __hip_bfloat16*)A + (size_t)ga * K + k0 + lcol);
    } else {
      if (ga < M) {
        const float* ap = (const float*)A + (size_t)ga * K + k0 + lcol;
        float4 f1 = *(const float4*)ap;
        float4 f2 = *(const float4*)(ap + 4);
        av.x = pk2(f1.x, f1.y); av.y = pk2(f1.z, f1.w);
        av.z = pk2(f2.x, f2.y); av.w = pk2(f2.z, f2.w);
      }
    }
    uint4 bv = *(const uint4*)(Bt + (size_t)(n0 + lrow) * K + k0 + lcol);
    __syncthreads();            // previous iteration's LDS reads done
    *(uint4*)(&As[lrow][lcol]) = av;
    *(uint4*)(&Bs[lrow][lcol]) = bv;
    __syncthreads();
    bf16x8 af[2], bfr[2];
    #pragma unroll
    for (int i = 0; i < 2; i++) {
      af[i]  = *(const bf16x8*)(&As[wm + i * 16 + lm][quad * 8]);
      bfr[i] = *(const bf16x8*)(&Bs[wn + i * 16 + lm][quad * 8]);
    }
    #pragma unroll
    for (int mi = 0; mi < 2; mi++)
      #pragma unroll
      for (int ni = 0; ni < 2; ni++)
        acc[mi][ni] = __builtin_amdgcn_mfma_f32_16x16x32_bf16(af[mi], bfr[ni], acc[mi][ni], 0, 0, 0);
  }
  // C/D layout: col = lane&15, row = quad*4 + r  (m89/m91 verified)
  #pragma unroll
  for (int mi = 0; mi < 2; mi++)
    #pragma unroll
    for (int ni = 0; ni < 2; ni++)
      #pragma unroll
      for (int r = 0; r < 4; r++) {
        int gm = m0 + wm + mi * 16 + quad * 4 + r;
        int gn = n0 + wn + ni * 16 + lm;
        if (gm < M) C[(size_t)gm * N + gn] = __float2bfloat16(acc[mi][ni][r]);
      }
}

// ---------------- el/er for HID=256/HEADS=8 layers: vectorized 16B/lane ----------------
__global__ void k_eler8(const uint4* __restrict__ feat_rows,   // [N][32] uint4
                        const float* __restrict__ al, const float* __restrict__ ar,
                        float* __restrict__ el, float* __restrict__ er) {
  int i = blockIdx.x * blockDim.x + threadIdx.x;   // (n,h)
  if (i >= N_NODES * HEADS) return;
  int n = i >> 3, h = i & 7;
  const uint4* base = feat_rows + (size_t)n * 32 + h * 4;
  const float* alh = al + h * DHEAD;
  const float* arh = ar + h * DHEAD;
  float sl = 0.f, sr = 0.f;
  #pragma unroll
  for (int q = 0; q < 4; q++) {
    uint4 v = base[q];
    unsigned u[4] = {v.x, v.y, v.z, v.w};
    #pragma unroll
    for (int w = 0; w < 4; w++) {
      int d = q * 8 + w * 2;
      float f0 = blo(u[w]), f1 = bhi(u[w]);
      sl += f0 * alh[d] + f1 * alh[d + 1];
      sr += f0 * arh[d] + f1 * arh[d + 1];
    }
  }
  el[i] = sl;
  er[i] = sr;
}

// ---------------- el/er for layer 2 (1 head, 40 dims, stride 64) ----------------
__global__ void k_eler2(const __hip_bfloat16* __restrict__ feat2,
                        const float* __restrict__ al, const float* __restrict__ ar,
                        float* __restrict__ el, float* __restrict__ er) {
  int n = blockIdx.x * blockDim.x + threadIdx.x;
  if (n >= N_NODES) return;
  const __hip_bfloat16* f = feat2 + (size_t)n * NCLS_PAD;
  float sl = 0.f, sr = 0.f;
  for (int d = 0; d < N_CLS; d++) {
    float v = __bfloat162float(f[d]);
    sl += v * al[d];
    sr += v * ar[d];
  }
  el[n] = sl;
  er[n] = sr;
}

// ---------------- fused edge-softmax + aggregation, 8 slots x 32 lanes ----------------
// lane owns 8 channels (uint4/edge). No max-subtraction (shift-invariant, exp clamped).
// Unroll-2: two independent csr->el/feat gather chains in flight (latency-bound fix).
__global__ __launch_bounds__(256) void k_aggregate8(const int* __restrict__ rowptr,
                                                    const int* __restrict__ csr_src,
                                                    const uint4* __restrict__ feat_rows,
                                                    const float* __restrict__ el,
                                                    const float* __restrict__ er,
                                                    const float* __restrict__ bias,
                                                    __hip_bfloat16* __restrict__ out) {
  __shared__ float lds_acc[8][256];
  __shared__ float lds_l[8][32];
  int n = blockIdx.x;
  int t = threadIdx.x;
  int slot = t >> 5;      // 0..7
  int c = t & 31;         // channel group: channels c*8..c*8+7
  int hh = c >> 2;        // head of this group
  float er_n = er[n * HEADS + hh];
  int beg = rowptr[n], end = rowptr[n + 1];
  float l = 0.f;
  float acc[8] = {0.f, 0.f, 0.f, 0.f, 0.f, 0.f, 0.f, 0.f};
  int i = beg + slot;
  for (; i + 8 < end; i += 16) {
    int s1 = csr_src[i];
    int s2 = csr_src[i + 8];
    float el1 = el[s1 * HEADS + hh];
    float el2 = el[s2 * HEADS + hh];
    uint4 f1 = feat_rows[(size_t)s1 * 32 + c];
    uint4 f2 = feat_rows[(size_t)s2 * 32 + c];
    float x1 = el1 + er_n, x2 = el2 + er_n;
    float e1 = x1 > 0.f ? x1 : 0.2f * x1;
    float e2 = x2 > 0.f ? x2 : 0.2f * x2;
    float p1 = __expf(fminf(e1, 60.f));
    float p2 = __expf(fminf(e2, 60.f));
    l += p1 + p2;
    acc[0] += p1 * blo(f1.x) + p2 * blo(f2.x); acc[1] += p1 * bhi(f1.x) + p2 * bhi(f2.x);
    acc[2] += p1 * blo(f1.y) + p2 * blo(f2.y); acc[3] += p1 * bhi(f1.y) + p2 * bhi(f2.y);
    acc[4] += p1 * blo(f1.z) + p2 * blo(f2.z); acc[5] += p1 * bhi(f1.z) + p2 * bhi(f2.z);
    acc[6] += p1 * blo(f1.w) + p2 * blo(f2.w); acc[7] += p1 * bhi(f1.w) + p2 * bhi(f2.w);
  }
  if (i < end) {
    int s = csr_src[i];
    float elv = el[s * HEADS + hh];
    uint4 fv = feat_rows[(size_t)s * 32 + c];
    float x = elv + er_n;
    float e = x > 0.f ? x : 0.2f * x;
    float p = __expf(fminf(e, 60.f));
    l += p;
    acc[0] += p * blo(fv.x); acc[1] += p * bhi(fv.x);
    acc[2] += p * blo(fv.y); acc[3] += p * bhi(fv.y);
    acc[4] += p * blo(fv.z); acc[5] += p * bhi(fv.z);
    acc[6] += p * blo(fv.w); acc[7] += p * bhi(fv.w);
  }
  *(float4*)&lds_acc[slot][c * 8]     = make_float4(acc[0], acc[1], acc[2], acc[3]);
  *(float4*)&lds_acc[slot][c * 8 + 4] = make_float4(acc[4], acc[5], acc[6], acc[7]);
  lds_l[slot][c] = l;
  __syncthreads();
  float a = 0.f, L = 0.f;
  #pragma unroll
  for (int s2 = 0; s2 < 8; s2++) { a += lds_acc[s2][t]; L += lds_l[s2][t >> 3]; }
  float o = a / fmaxf(L, 1e-9f) + bias[t];
  o = fmaxf(o, 0.f);                            // ReLU (layers 0,1)
  out[(size_t)n * HID + t] = __float2bfloat16(o);
}

// ---------------- layer 2 aggregate: 32 slots x 8 lanes (64-ch padded rows) ----------------
__global__ __launch_bounds__(256) void k_aggregate1(const int* __restrict__ rowptr,
                                                    const int* __restrict__ csr_src,
                                                    const uint4* __restrict__ fr2,  // [N][8] uint4
                                                    const float* __restrict__ el,
                                                    const float* __restrict__ er,
                                                    const float* __restrict__ bias,
                                                    void* __restrict__ out,
                                                    const int* __restrict__ flag) {
  __shared__ float lds_acc[32][64];
  __shared__ float lds_l[32][8];
  int isbf = *flag;
  int n = blockIdx.x;
  int t = threadIdx.x;
  int slot = t >> 3;      // 0..31
  int c = t & 7;
  float er_n = er[n];
  int beg = rowptr[n], end = rowptr[n + 1];
  float l = 0.f;
  float acc[8] = {0.f, 0.f, 0.f, 0.f, 0.f, 0.f, 0.f, 0.f};
  int i = beg + slot;
  for (; i + 32 < end; i += 64) {
    int s1 = csr_src[i], s2 = csr_src[i + 32];
    float el1 = el[s1], el2 = el[s2];
    uint4 f1 = fr2[(size_t)s1 * 8 + c];
    uint4 f2 = fr2[(size_t)s2 * 8 + c];
    float x1 = el1 + er_n, x2 = el2 + er_n;
    float e1 = x1 > 0.f ? x1 : 0.2f * x1;
    float e2 = x2 > 0.f ? x2 : 0.2f * x2;
    float p1 = __expf(fminf(e1, 60.f));
    float p2 = __expf(fminf(e2, 60.f));
    l += p1 + p2;
    acc[0] += p1 * blo(f1.x) + p2 * blo(f2.x); acc[1] += p1 * bhi(f1.x) + p2 * bhi(f2.x);
    acc[2] += p1 * blo(f1.y) + p2 * blo(f2.y); acc[3] += p1 * bhi(f1.y) + p2 * bhi(f2.y);
    acc[4] += p1 * blo(f1.z) + p2 * blo(f2.z); acc[5] += p1 * bhi(f1.z) + p2 * bhi(f2.z);
    acc[6] += p1 * blo(f1.w) + p2 * blo(f2.w); acc[7] += p1 * bhi(f1.w) + p2 * bhi(f2.w);
  }
  if (i < end) {
    int s = csr_src[i];
    float x = el[s] + er_n;
    uint4 fv = fr2[(size_t)s * 8 + c];
    float e = x > 0.f ? x : 0.2f * x;
    float p = __expf(fminf(e, 60.f));
    l += p;
    acc[0] += p * blo(fv.x); acc[1] += p * bhi(fv.x);
    acc[2] += p * blo(fv.y); acc[3] += p * bhi(fv.y);
    acc[4] += p * blo(fv.z); acc[5] += p * bhi(fv.z);
    acc[6] += p * blo(fv.w); acc[7] += p * bhi(fv.w);
  }
  *(float4*)&lds_acc[slot][c * 8]     = make_float4(acc[0], acc[1], acc[2], acc[3]);
  *(float4*)&lds_acc[slot][c * 8 + 4] = make_float4(acc[4], acc[5], acc[6], acc[7]);
  lds_l[slot][c] = l;
  __syncthreads();
  if (t < N_CLS) {
    float a = 0.f, L = 0.f;
    #pragma unroll
    for (int s2 = 0; s2 < 32; s2++) { a += lds_acc[s2][t]; L += lds_l[s2][t >> 3]; }
    float o = a / fmaxf(L, 1e-9f) + bias[t];    // no ReLU on output layer
    if (isbf) ((__hip_bfloat16*)out)[(size_t)n * N_CLS + t] = __float2bfloat16(o);
    else      ((float*)out)[(size_t)n * N_CLS + t] = o;
  }
}

// ---------------- launch ----------------
static inline size_t align_up(size_t x) { return (x + 255) & ~(size_t)255; }

extern "C" void kernel_launch(void* const* d_in, const int* in_sizes, int n_in,
                              void* d_out, int out_size, void* d_ws, size_t ws_size,
                              hipStream_t stream) {
  const void* in_feat = d_in[0];
  const int* src = (const int*)d_in[1];
  const int* dst = (const int*)d_in[2];
  const void* W0  = d_in[3];
  const void* al0 = d_in[4];
  const void* ar0 = d_in[5];
  const void* b0  = d_in[6];
  const void* W1  = d_in[7];
  const void* al1 = d_in[8];
  const void* ar1 = d_in[9];
  const void* b1  = d_in[10];
  const void* W2  = d_in[11];
  const void* al2 = d_in[12];
  const void* ar2 = d_in[13];
  const void* b2  = d_in[14];

  char* p = (char*)d_ws;
  int* flag = (int*)p;                   p += 256;
  float* att = (float*)p;                p += align_up(AT_SZ * sizeof(float));
  int* rowptr = (int*)p;                 p += align_up((N_NODES + 1) * sizeof(int));
  int* cursor = (int*)p;                 p += align_up(N_NODES * sizeof(int));
  int* csr_src = (int*)p;                p += align_up(N_EDGES * sizeof(int));
  int* partial = (int*)p;                p += align_up(SCAN_NB * sizeof(int));
  __hip_bfloat16* feat16 = (__hip_bfloat16*)p; p += align_up((size_t)N_NODES * HID * sizeof(__hip_bfloat16));
  __hip_bfloat16* h16 = (__hip_bfloat16*)p;    p += align_up((size_t)N_NODES * HID * sizeof(__hip_bfloat16));
  float* el = (float*)p;                 p += align_up((size_t)N_NODES * HEADS * sizeof(float));
  float* er = (float*)p;                 p += align_up((size_t)N_NODES * HEADS * sizeof(float));
  __hip_bfloat16* w0t = (__hip_bfloat16*)p;    p += align_up((size_t)HID * IN_F * sizeof(__hip_bfloat16));
  __hip_bfloat16* w1t = (__hip_bfloat16*)p;    p += align_up((size_t)HID * HID * sizeof(__hip_bfloat16));
  __hip_bfloat16* w2t = (__hip_bfloat16*)p;    p += align_up((size_t)NCLS_PAD * HID * sizeof(__hip_bfloat16));

  const int EB = (N_EDGES + 255) / 256;
  const int MB64 = (N_NODES + 63) / 64;

  // ---- dtype detection + constant prep ----
  k_detect_prep<<<1, 256, 0, stream>>>((const unsigned short*)in_feat, flag,
                                       al0, ar0, al1, ar1, al2, ar2, b0, b1, b2, att);

  // ---- CSR build ----
  hipMemsetAsync(cursor, 0, N_NODES * sizeof(int), stream);
  k_hist<<<EB, 256, 0, stream>>>(dst, cursor);
  k_scan_blocks<<<SCAN_NB, SCAN_B, 0, stream>>>(cursor, rowptr, partial);
  k_scan_partials<<<1, 128, 0, stream>>>(partial, rowptr);
  k_scan_add<<<(N_NODES + 255) / 256, 256, 0, stream>>>(rowptr, partial);
  hipMemsetAsync(cursor, 0, N_NODES * sizeof(int), stream);
  k_scatter<<<EB, 256, 0, stream>>>(src, dst, rowptr, cursor, csr_src);

  // ---- weight transposes (-> bf16 [N][K]) ----
  k_transpose16<<<(HID * IN_F + 255) / 256, 256, 0, stream>>>(W0, w0t, IN_F, HID, HID, flag);
  k_transpose16<<<(HID * HID + 255) / 256, 256, 0, stream>>>(W1, w1t, HID, HID, HID, flag);
  k_transpose16<<<(NCLS_PAD * HID + 255) / 256, 256, 0, stream>>>(W2, w2t, HID, N_CLS, NCLS_PAD, flag);

  // ---- layer 0 (f32->bf16 cast fused into GEMM A-staging) ----
  k_gemm64<<<dim3(MB64, HID / 64), 256, 0, stream>>>(in_feat, w0t, feat16, N_NODES, IN_F, HID, flag, 0);
  k_eler8<<<(N_NODES * HEADS + 255) / 256, 256, 0, stream>>>((const uint4*)feat16, att + AT_AL0, att + AT_AR0, el, er);
  k_aggregate8<<<N_NODES, 256, 0, stream>>>(rowptr, csr_src, (const uint4*)feat16, el, er, att + AT_B0, h16);

  // ---- layer 1 ----
  k_gemm64<<<dim3(MB64, HID / 64), 256, 0, stream>>>(h16, w1t, feat16, N_NODES, HID, HID, flag, 1);
  k_eler8<<<(N_NODES * HEADS + 255) / 256, 256, 0, stream>>>((const uint4*)feat16, att + AT_AL1, att + AT_AR1, el, er);
  k_aggregate8<<<N_NODES, 256, 0, stream>>>(rowptr, csr_src, (const uint4*)feat16, el, er, att + AT_B1, h16);

  // ---- layer 2 (feat16 reused as [N][64] padded feat2) ----
  k_gemm64<<<dim3(MB64, 1), 256, 0, stream>>>(h16, w2t, feat16, N_NODES, HID, NCLS_PAD, flag, 1);
  k_eler2<<<(N_NODES + 255) / 256, 256, 0, stream>>>(feat16, att + AT_AL2, att + AT_AR2, el, er);
  k_aggregate1<<<N_NODES, 256, 0, stream>>>(rowptr, csr_src, (const uint4*)feat16, el, er, att + AT_B2, d_out, flag);
}

// Round 7
// 553.153 us; speedup vs baseline: 1.1564x; 1.0314x over previous
//
#include <hip/hip_runtime.h>
#include <hip/hip_bf16.h>

#define N_NODES 50000
#define N_EDGES 800000
#define IN_F 512
#define HID 256
#define HEADS 8
#define DHEAD 32
#define N_CLS 40
#define NCLS_PAD 64

typedef __bf16 bf16x8 __attribute__((ext_vector_type(8)));
typedef float f32x4 __attribute__((ext_vector_type(4)));

// f32 att/bias workspace layout (in floats)
#define AT_AL0 0
#define AT_AR0 256
#define AT_AL1 512
#define AT_AR1 768
#define AT_AL2 1024
#define AT_AR2 1088
#define AT_B0  1152
#define AT_B1  1408
#define AT_B2  1664
#define AT_SZ  1792

__device__ __forceinline__ float ldflag(const void* p, long long i, int isbf) {
  return isbf ? __bfloat162float(((const __hip_bfloat16*)p)[i])
              : ((const float*)p)[i];
}
// unpack a packed bf16 pair (u32): low-address element in low 16 bits
__device__ __forceinline__ float blo(unsigned u) { return __uint_as_float(u << 16); }
__device__ __forceinline__ float bhi(unsigned u) { return __uint_as_float(u & 0xffff0000u); }
// pack two floats -> bf16 pair in u32
__device__ __forceinline__ unsigned pk2(float a, float b) {
  unsigned x = __bfloat16_as_ushort(__float2bfloat16(a));
  unsigned y = __bfloat16_as_ushort(__float2bfloat16(b));
  return x | (y << 16);
}

// ---------------- dtype detect + constant prep + cursor zero (1 block) ----------------
__global__ void k_detect_prep(const unsigned short* __restrict__ raw, int* __restrict__ flag,
                              const void* al0, const void* ar0, const void* al1, const void* ar1,
                              const void* al2, const void* ar2, const void* b0, const void* b1,
                              const void* b2, float* __restrict__ att, int* __restrict__ cursor) {
  __shared__ int cnt[256];
  int t = threadIdx.x;
  // zero the histogram buffer (replaces hipMemsetAsync #1)
  for (int i = t; i < N_NODES; i += 256) cursor[i] = 0;
  int c = 0;
  for (int i = t; i < 8192; i += 256) {
    int e = (raw[i] >> 7) & 0xFF;
    if (e >= 0x90) c++;
  }
  cnt[t] = c;
  __syncthreads();
  for (int s = 128; s; s >>= 1) {
    if (t < s) cnt[t] += cnt[t + s];
    __syncthreads();
  }
  __shared__ int sflag;
  if (t == 0) { sflag = (cnt[0] > 64) ? 0 : 1; *flag = sflag; }
  __syncthreads();
  int isbf = sflag;
  att[AT_AL0 + t] = ldflag(al0, t, isbf);
  att[AT_AR0 + t] = ldflag(ar0, t, isbf);
  att[AT_AL1 + t] = ldflag(al1, t, isbf);
  att[AT_AR1 + t] = ldflag(ar1, t, isbf);
  att[AT_B0 + t]  = ldflag(b0, t, isbf);
  att[AT_B1 + t]  = ldflag(b1, t, isbf);
  if (t < N_CLS) {
    att[AT_AL2 + t] = ldflag(al2, t, isbf);
    att[AT_AR2 + t] = ldflag(ar2, t, isbf);
    att[AT_B2 + t]  = ldflag(b2, t, isbf);
  }
}

// ---------------- CSR build (by dst) ----------------
__global__ void k_hist(const int* __restrict__ dst, int* __restrict__ cnt) {
  int e = blockIdx.x * blockDim.x + threadIdx.x;
  if (e < N_EDGES) atomicAdd(&cnt[dst[e]], 1);
}

#define SCAN_B 512
#define SCAN_NB ((N_NODES + SCAN_B - 1) / SCAN_B)   // 98

__global__ __launch_bounds__(SCAN_B) void k_scan_blocks(const int* __restrict__ deg,
                                                        int* __restrict__ excl,
                                                        int* __restrict__ partial) {
  __shared__ int buf[SCAN_B];
  int t = threadIdx.x;
  int i = blockIdx.x * SCAN_B + t;
  int v = (i < N_NODES) ? deg[i] : 0;
  buf[t] = v;
  __syncthreads();
  for (int off = 1; off < SCAN_B; off <<= 1) {
    int x = (t >= off) ? buf[t - off] : 0;
    __syncthreads();
    buf[t] += x;
    __syncthreads();
  }
  if (i < N_NODES) excl[i] = buf[t] - v;
  if (t == SCAN_B - 1) partial[blockIdx.x] = buf[t];
}

__global__ void k_scan_partials(int* __restrict__ partial, int* __restrict__ rowptr) {
  __shared__ int buf[SCAN_NB];
  int t = threadIdx.x;
  if (t < SCAN_NB) buf[t] = partial[t];
  __syncthreads();
  if (t == 0) {
    int run = 0;
    for (int b = 0; b < SCAN_NB; b++) { int v = buf[b]; buf[b] = run; run += v; }
    rowptr[N_NODES] = run;
  }
  __syncthreads();
  if (t < SCAN_NB) partial[t] = buf[t];
}

// adds partial sums AND re-zeros cursor for k_scatter (replaces hipMemsetAsync #2;
// safe: scan_blocks already consumed the degree values from cursor)
__global__ void k_scan_add(int* __restrict__ rowptr, const int* __restrict__ partial,
                           int* __restrict__ cursor) {
  int i = blockIdx.x * blockDim.x + threadIdx.x;
  if (i < N_NODES) {
    rowptr[i] += partial[i / SCAN_B];
    cursor[i] = 0;
  }
}

__global__ void k_scatter(const int* __restrict__ src, const int* __restrict__ dst,
                          const int* __restrict__ rowptr, int* __restrict__ cursor,
                          int* __restrict__ csr_src) {
  int e = blockIdx.x * blockDim.x + threadIdx.x;
  if (e < N_EDGES) {
    int d = dst[e];
    int pos = rowptr[d] + atomicAdd(&cursor[d], 1);
    csr_src[pos] = src[e];
  }
}

// ---------------- all 3 weight transposes in one kernel -> bf16 [Ndst][K] ----------------
#define TW0 (HID * IN_F)            // 131072
#define TW1 (TW0 + HID * HID)       // 196608
#define TW2 (TW1 + NCLS_PAD * HID)  // 212992
__global__ void k_transpose_all(const void* __restrict__ W0, const void* __restrict__ W1,
                                const void* __restrict__ W2,
                                __hip_bfloat16* __restrict__ w0t, __hip_bfloat16* __restrict__ w1t,
                                __hip_bfloat16* __restrict__ w2t, const int* __restrict__ flag) {
  int isbf = *flag;
  int i = blockIdx.x * blockDim.x + threadIdx.x;
  if (i < TW0) {                       // w0t[256][512] <- W0[512][256]
    int n = i >> 9, k = i & 511;
    w0t[i] = __float2bfloat16(ldflag(W0, (long long)k * HID + n, isbf));
  } else if (i < TW1) {                // w1t[256][256] <- W1[256][256]
    int j = i - TW0;
    int n = j >> 8, k = j & 255;
    w1t[j] = __float2bfloat16(ldflag(W1, (long long)k * HID + n, isbf));
  } else if (i < TW2) {                // w2t[64][256] <- W2[256][40], pad cols 40..63
    int j = i - TW1;
    int n = j >> 8, k = j & 255;
    float v = (n < N_CLS) ? ldflag(W2, (long long)k * N_CLS + n, isbf) : 0.f;
    w2t[j] = __float2bfloat16(v);
  }
}

// ---------------- MFMA bf16 GEMM, 64x64 tile, XCD-swizzled, dual-dtype A ----------------
// C[M][N] = A[M][K] * Bt[N][K]^T. Block mapping: groups of 8 m-tiles x nblk n-tiles;
// within a group, the nblk blocks sharing one A-tile have linear ids {j, j+8, j+16, j+24}
// -> same %8 residue (same XCD under round-robin) and <=32 ids apart (co-resident), so
// the A-tile is fetched once into that XCD's L2 and re-read from L2, not L3/HBM.
// Grid stays ~3128 blocks (round-5 lesson: oversubscription is what hides latency).
__global__ __launch_bounds__(256) void k_gemm64(const void* __restrict__ A,
                                                const __hip_bfloat16* __restrict__ Bt,
                                                __hip_bfloat16* __restrict__ C,
                                                int M, int K, int N,
                                                const int* __restrict__ flag, int force_bf) {
  __shared__ unsigned short As[64][40];  // 80 B pitch: 16B-aligned rows, spreads banks
  __shared__ unsigned short Bs[64][40];
  const int isbf = force_bf ? 1 : *flag;
  int nblk = N >> 6;
  int per = nblk << 3;                 // blocks per group
  int g = blockIdx.x / per;
  int i2 = blockIdx.x - g * per;
  int mb = g * 8 + (i2 & 7);
  int nb = i2 >> 3;
  int m0 = mb * 64, n0 = nb * 64;
  if (m0 >= M) return;
  int tid = threadIdx.x;
  int lrow = tid >> 2;          // 0..63
  int lcol = (tid & 3) * 8;     // 0,8,16,24
  int wave = tid >> 6, lane = tid & 63;
  int wm = (wave >> 1) * 32, wn = (wave & 1) * 32;
  int lm = lane & 15, quad = lane >> 4;
  f32x4 acc[2][2] = {};
  for (int k0 = 0; k0 < K; k0 += 32) {
    int ga = m0 + lrow;
    uint4 av = make_uint4(0u, 0u, 0u, 0u);
    if (isbf) {
      if (ga < M) av = *(const uint4*)((const __hip_bfloat16*)A + (size_t)ga * K + k0 + lcol);
    } else {
      if (ga < M) {
        const float* ap = (const float*)A + (size_t)ga * K + k0 + lcol;
        float4 f1 = *(const float4*)ap;
        float4 f2 = *(const float4*)(ap + 4);
        av.x = pk2(f1.x, f1.y); av.y = pk2(f1.z, f1.w);
        av.z = pk2(f2.x, f2.y); av.w = pk2(f2.z, f2.w);
      }
    }
    uint4 bv = *(const uint4*)(Bt + (size_t)(n0 + lrow) * K + k0 + lcol);
    __syncthreads();            // previous iteration's LDS reads done
    *(uint4*)(&As[lrow][lcol]) = av;
    *(uint4*)(&Bs[lrow][lcol]) = bv;
    __syncthreads();
    bf16x8 af[2], bfr[2];
    #pragma unroll
    for (int i = 0; i < 2; i++) {
      af[i]  = *(const bf16x8*)(&As[wm + i * 16 + lm][quad * 8]);
      bfr[i] = *(const bf16x8*)(&Bs[wn + i * 16 + lm][quad * 8]);
    }
    #pragma unroll
    for (int mi = 0; mi < 2; mi++)
      #pragma unroll
      for (int ni = 0; ni < 2; ni++)
        acc[mi][ni] = __builtin_amdgcn_mfma_f32_16x16x32_bf16(af[mi], bfr[ni], acc[mi][ni], 0, 0, 0);
  }
  // C/D layout: col = lane&15, row = quad*4 + r  (m89/m91 verified)
  #pragma unroll
  for (int mi = 0; mi < 2; mi++)
    #pragma unroll
    for (int ni = 0; ni < 2; ni++)
      #pragma unroll
      for (int r = 0; r < 4; r++) {
        int gm = m0 + wm + mi * 16 + quad * 4 + r;
        int gn = n0 + wn + ni * 16 + lm;
        if (gm < M) C[(size_t)gm * N + gn] = __float2bfloat16(acc[mi][ni][r]);
      }
}

// ---------------- el/er for HID=256/HEADS=8 layers: vectorized 16B/lane ----------------
__global__ void k_eler8(const uint4* __restrict__ feat_rows,   // [N][32] uint4
                        const float* __restrict__ al, const float* __restrict__ ar,
                        float* __restrict__ el, float* __restrict__ er) {
  int i = blockIdx.x * blockDim.x + threadIdx.x;   // (n,h)
  if (i >= N_NODES * HEADS) return;
  int n = i >> 3, h = i & 7;
  const uint4* base = feat_rows + (size_t)n * 32 + h * 4;
  const float* alh = al + h * DHEAD;
  const float* arh = ar + h * DHEAD;
  float sl = 0.f, sr = 0.f;
  #pragma unroll
  for (int q = 0; q < 4; q++) {
    uint4 v = base[q];
    unsigned u[4] = {v.x, v.y, v.z, v.w};
    #pragma unroll
    for (int w = 0; w < 4; w++) {
      int d = q * 8 + w * 2;
      float f0 = blo(u[w]), f1 = bhi(u[w]);
      sl += f0 * alh[d] + f1 * alh[d + 1];
      sr += f0 * arh[d] + f1 * arh[d + 1];
    }
  }
  el[i] = sl;
  er[i] = sr;
}

// ---------------- el/er for layer 2 (1 head, 40 dims, stride 64) ----------------
__global__ void k_eler2(const __hip_bfloat16* __restrict__ feat2,
                        const float* __restrict__ al, const float* __restrict__ ar,
                        float* __restrict__ el, float* __restrict__ er) {
  int n = blockIdx.x * blockDim.x + threadIdx.x;
  if (n >= N_NODES) return;
  const __hip_bfloat16* f = feat2 + (size_t)n * NCLS_PAD;
  float sl = 0.f, sr = 0.f;
  for (int d = 0; d < N_CLS; d++) {
    float v = __bfloat162float(f[d]);
    sl += v * al[d];
    sr += v * ar[d];
  }
  el[n] = sl;
  er[n] = sr;
}

// ---------------- fused edge-softmax + aggregation, 8 slots x 32 lanes ----------------
// lane owns 8 channels (uint4/edge). No max-subtraction (shift-invariant, exp clamped).
// Unroll-2: two independent csr->el/feat gather chains in flight (latency-bound fix).
__global__ __launch_bounds__(256) void k_aggregate8(const int* __restrict__ rowptr,
                                                    const int* __restrict__ csr_src,
                                                    const uint4* __restrict__ feat_rows,
                                                    const float* __restrict__ el,
                                                    const float* __restrict__ er,
                                                    const float* __restrict__ bias,
                                                    __hip_bfloat16* __restrict__ out) {
  __shared__ float lds_acc[8][256];
  __shared__ float lds_l[8][32];
  int n = blockIdx.x;
  int t = threadIdx.x;
  int slot = t >> 5;      // 0..7
  int c = t & 31;         // channel group: channels c*8..c*8+7
  int hh = c >> 2;        // head of this group
  float er_n = er[n * HEADS + hh];
  int beg = rowptr[n], end = rowptr[n + 1];
  float l = 0.f;
  float acc[8] = {0.f, 0.f, 0.f, 0.f, 0.f, 0.f, 0.f, 0.f};
  int i = beg + slot;
  for (; i + 8 < end; i += 16) {
    int s1 = csr_src[i];
    int s2 = csr_src[i + 8];
    float el1 = el[s1 * HEADS + hh];
    float el2 = el[s2 * HEADS + hh];
    uint4 f1 = feat_rows[(size_t)s1 * 32 + c];
    uint4 f2 = feat_rows[(size_t)s2 * 32 + c];
    float x1 = el1 + er_n, x2 = el2 + er_n;
    float e1 = x1 > 0.f ? x1 : 0.2f * x1;
    float e2 = x2 > 0.f ? x2 : 0.2f * x2;
    float p1 = __expf(fminf(e1, 60.f));
    float p2 = __expf(fminf(e2, 60.f));
    l += p1 + p2;
    acc[0] += p1 * blo(f1.x) + p2 * blo(f2.x); acc[1] += p1 * bhi(f1.x) + p2 * bhi(f2.x);
    acc[2] += p1 * blo(f1.y) + p2 * blo(f2.y); acc[3] += p1 * bhi(f1.y) + p2 * bhi(f2.y);
    acc[4] += p1 * blo(f1.z) + p2 * blo(f2.z); acc[5] += p1 * bhi(f1.z) + p2 * bhi(f2.z);
    acc[6] += p1 * blo(f1.w) + p2 * blo(f2.w); acc[7] += p1 * bhi(f1.w) + p2 * bhi(f2.w);
  }
  if (i < end) {
    int s = csr_src[i];
    float elv = el[s * HEADS + hh];
    uint4 fv = feat_rows[(size_t)s * 32 + c];
    float x = elv + er_n;
    float e = x > 0.f ? x : 0.2f * x;
    float p = __expf(fminf(e, 60.f));
    l += p;
    acc[0] += p * blo(fv.x); acc[1] += p * bhi(fv.x);
    acc[2] += p * blo(fv.y); acc[3] += p * bhi(fv.y);
    acc[4] += p * blo(fv.z); acc[5] += p * bhi(fv.z);
    acc[6] += p * blo(fv.w); acc[7] += p * bhi(fv.w);
  }
  *(float4*)&lds_acc[slot][c * 8]     = make_float4(acc[0], acc[1], acc[2], acc[3]);
  *(float4*)&lds_acc[slot][c * 8 + 4] = make_float4(acc[4], acc[5], acc[6], acc[7]);
  lds_l[slot][c] = l;
  __syncthreads();
  float a = 0.f, L = 0.f;
  #pragma unroll
  for (int s2 = 0; s2 < 8; s2++) { a += lds_acc[s2][t]; L += lds_l[s2][t >> 3]; }
  float o = a / fmaxf(L, 1e-9f) + bias[t];
  o = fmaxf(o, 0.f);                            // ReLU (layers 0,1)
  out[(size_t)n * HID + t] = __float2bfloat16(o);
}

// ---------------- layer 2 aggregate: 32 slots x 8 lanes (64-ch padded rows) ----------------
__global__ __launch_bounds__(256) void k_aggregate1(const int* __restrict__ rowptr,
                                                    const int* __restrict__ csr_src,
                                                    const uint4* __restrict__ fr2,  // [N][8] uint4
                                                    const float* __restrict__ el,
                                                    const float* __restrict__ er,
                                                    const float* __restrict__ bias,
                                                    void* __restrict__ out,
                                                    const int* __restrict__ flag) {
  __shared__ float lds_acc[32][64];
  __shared__ float lds_l[32][8];
  int isbf = *flag;
  int n = blockIdx.x;
  int t = threadIdx.x;
  int slot = t >> 3;      // 0..31
  int c = t & 7;
  float er_n = er[n];
  int beg = rowptr[n], end = rowptr[n + 1];
  float l = 0.f;
  float acc[8] = {0.f, 0.f, 0.f, 0.f, 0.f, 0.f, 0.f, 0.f};
  int i = beg + slot;
  for (; i + 32 < end; i += 64) {
    int s1 = csr_src[i], s2 = csr_src[i + 32];
    float el1 = el[s1], el2 = el[s2];
    uint4 f1 = fr2[(size_t)s1 * 8 + c];
    uint4 f2 = fr2[(size_t)s2 * 8 + c];
    float x1 = el1 + er_n, x2 = el2 + er_n;
    float e1 = x1 > 0.f ? x1 : 0.2f * x1;
    float e2 = x2 > 0.f ? x2 : 0.2f * x2;
    float p1 = __expf(fminf(e1, 60.f));
    float p2 = __expf(fminf(e2, 60.f));
    l += p1 + p2;
    acc[0] += p1 * blo(f1.x) + p2 * blo(f2.x); acc[1] += p1 * bhi(f1.x) + p2 * bhi(f2.x);
    acc[2] += p1 * blo(f1.y) + p2 * blo(f2.y); acc[3] += p1 * bhi(f1.y) + p2 * bhi(f2.y);
    acc[4] += p1 * blo(f1.z) + p2 * blo(f2.z); acc[5] += p1 * bhi(f1.z) + p2 * bhi(f2.z);
    acc[6] += p1 * blo(f1.w) + p2 * blo(f2.w); acc[7] += p1 * bhi(f1.w) + p2 * bhi(f2.w);
  }
  if (i < end) {
    int s = csr_src[i];
    float x = el[s] + er_n;
    uint4 fv = fr2[(size_t)s * 8 + c];
    float e = x > 0.f ? x : 0.2f * x;
    float p = __expf(fminf(e, 60.f));
    l += p;
    acc[0] += p * blo(fv.x); acc[1] += p * bhi(fv.x);
    acc[2] += p * blo(fv.y); acc[3] += p * bhi(fv.y);
    acc[4] += p * blo(fv.z); acc[5] += p * bhi(fv.z);
    acc[6] += p * blo(fv.w); acc[7] += p * bhi(fv.w);
  }
  *(float4*)&lds_acc[slot][c * 8]     = make_float4(acc[0], acc[1], acc[2], acc[3]);
  *(float4*)&lds_acc[slot][c * 8 + 4] = make_float4(acc[4], acc[5], acc[6], acc[7]);
  lds_l[slot][c] = l;
  __syncthreads();
  if (t < N_CLS) {
    float a = 0.f, L = 0.f;
    #pragma unroll
    for (int s2 = 0; s2 < 32; s2++) { a += lds_acc[s2][t]; L += lds_l[s2][t >> 3]; }
    float o = a / fmaxf(L, 1e-9f) + bias[t];    // no ReLU on output layer
    if (isbf) ((__hip_bfloat16*)out)[(size_t)n * N_CLS + t] = __float2bfloat16(o);
    else      ((float*)out)[(size_t)n * N_CLS + t] = o;
  }
}

// ---------------- launch ----------------
static inline size_t align_up(size_t x) { return (x + 255) & ~(size_t)255; }

extern "C" void kernel_launch(void* const* d_in, const int* in_sizes, int n_in,
                              void* d_out, int out_size, void* d_ws, size_t ws_size,
                              hipStream_t stream) {
  const void* in_feat = d_in[0];
  const int* src = (const int*)d_in[1];
  const int* dst = (const int*)d_in[2];
  const void* W0  = d_in[3];
  const void* al0 = d_in[4];
  const void* ar0 = d_in[5];
  const void* b0  = d_in[6];
  const void* W1  = d_in[7];
  const void* al1 = d_in[8];
  const void* ar1 = d_in[9];
  const void* b1  = d_in[10];
  const void* W2  = d_in[11];
  const void* al2 = d_in[12];
  const void* ar2 = d_in[13];
  const void* b2  = d_in[14];

  char* p = (char*)d_ws;
  int* flag = (int*)p;                   p += 256;
  float* att = (float*)p;                p += align_up(AT_SZ * sizeof(float));
  int* rowptr = (int*)p;                 p += align_up((N_NODES + 1) * sizeof(int));
  int* cursor = (int*)p;                 p += align_up(N_NODES * sizeof(int));
  int* csr_src = (int*)p;                p += align_up(N_EDGES * sizeof(int));
  int* partial = (int*)p;                p += align_up(SCAN_NB * sizeof(int));
  __hip_bfloat16* feat16 = (__hip_bfloat16*)p; p += align_up((size_t)N_NODES * HID * sizeof(__hip_bfloat16));
  __hip_bfloat16* h16 = (__hip_bfloat16*)p;    p += align_up((size_t)N_NODES * HID * sizeof(__hip_bfloat16));
  float* el = (float*)p;                 p += align_up((size_t)N_NODES * HEADS * sizeof(float));
  float* er = (float*)p;                 p += align_up((size_t)N_NODES * HEADS * sizeof(float));
  __hip_bfloat16* w0t = (__hip_bfloat16*)p;    p += align_up((size_t)HID * IN_F * sizeof(__hip_bfloat16));
  __hip_bfloat16* w1t = (__hip_bfloat16*)p;    p += align_up((size_t)HID * HID * sizeof(__hip_bfloat16));
  __hip_bfloat16* w2t = (__hip_bfloat16*)p;    p += align_up((size_t)NCLS_PAD * HID * sizeof(__hip_bfloat16));

  const int EB = (N_EDGES + 255) / 256;
  const int MB64 = (N_NODES + 63) / 64;          // 782
  const int GROUPS = (MB64 + 7) / 8;             // 98
  const int G4 = GROUPS * 8 * 4;                 // swizzled grid, nblk=4 (3136)
  const int G1 = GROUPS * 8 * 1;                 // swizzled grid, nblk=1 (784)

  // ---- dtype detection + constant prep + cursor zero ----
  k_detect_prep<<<1, 256, 0, stream>>>((const unsigned short*)in_feat, flag,
                                       al0, ar0, al1, ar1, al2, ar2, b0, b1, b2, att, cursor);

  // ---- CSR build ----
  k_hist<<<EB, 256, 0, stream>>>(dst, cursor);
  k_scan_blocks<<<SCAN_NB, SCAN_B, 0, stream>>>(cursor, rowptr, partial);
  k_scan_partials<<<1, 128, 0, stream>>>(partial, rowptr);
  k_scan_add<<<(N_NODES + 255) / 256, 256, 0, stream>>>(rowptr, partial, cursor);
  k_scatter<<<EB, 256, 0, stream>>>(src, dst, rowptr, cursor, csr_src);

  // ---- weight transposes (merged, -> bf16 [N][K]) ----
  k_transpose_all<<<(TW2 + 255) / 256, 256, 0, stream>>>(W0, W1, W2, w0t, w1t, w2t, flag);

  // ---- layer 0 (f32->bf16 cast fused into GEMM A-staging) ----
  k_gemm64<<<G4, 256, 0, stream>>>(in_feat, w0t, feat16, N_NODES, IN_F, HID, flag, 0);
  k_eler8<<<(N_NODES * HEADS + 255) / 256, 256, 0, stream>>>((const uint4*)feat16, att + AT_AL0, att + AT_AR0, el, er);
  k_aggregate8<<<N_NODES, 256, 0, stream>>>(rowptr, csr_src, (const uint4*)feat16, el, er, att + AT_B0, h16);

  // ---- layer 1 ----
  k_gemm64<<<G4, 256, 0, stream>>>(h16, w1t, feat16, N_NODES, HID, HID, flag, 1);
  k_eler8<<<(N_NODES * HEADS + 255) / 256, 256, 0, stream>>>((const uint4*)feat16, att + AT_AL1, att + AT_AR1, el, er);
  k_aggregate8<<<N_NODES, 256, 0, stream>>>(rowptr, csr_src, (const uint4*)feat16, el, er, att + AT_B1, h16);

  // ---- layer 2 (feat16 reused as [N][64] padded feat2) ----
  k_gemm64<<<G1, 256, 0, stream>>>(h16, w2t, feat16, N_NODES, HID, NCLS_PAD, flag, 1);
  k_eler2<<<(N_NODES + 255) / 256, 256, 0, stream>>>(feat16, att + AT_AL2, att + AT_AR2, el, er);
  k_aggregate1<<<N_NODES, 256, 0, stream>>>(rowptr, csr_src, (const uint4*)feat16, el, er, att + AT_B2, d_out, flag);
}

// Round 8
// 532.662 us; speedup vs baseline: 1.2008x; 1.0385x over previous
//
#include <hip/hip_runtime.h>
#include <hip/hip_bf16.h>

#define N_NODES 50000
#define N_EDGES 800000
#define IN_F 512
#define HID 256
#define HEADS 8
#define DHEAD 32
#define N_CLS 40
#define NCLS_PAD 64

typedef __bf16 bf16x8 __attribute__((ext_vector_type(8)));
typedef float f32x4 __attribute__((ext_vector_type(4)));

// f32 att/bias workspace layout (in floats)
#define AT_AL0 0
#define AT_AR0 256
#define AT_AL1 512
#define AT_AR1 768
#define AT_AL2 1024
#define AT_AR2 1088
#define AT_B0  1152
#define AT_B1  1408
#define AT_B2  1664
#define AT_SZ  1792

__device__ __forceinline__ float ldflag(const void* p, long long i, int isbf) {
  return isbf ? __bfloat162float(((const __hip_bfloat16*)p)[i])
              : ((const float*)p)[i];
}
// unpack a packed bf16 pair (u32): low-address element in low 16 bits
__device__ __forceinline__ float blo(unsigned u) { return __uint_as_float(u << 16); }
__device__ __forceinline__ float bhi(unsigned u) { return __uint_as_float(u & 0xffff0000u); }
// pack two floats -> bf16 pair in u32
__device__ __forceinline__ unsigned pk2(float a, float b) {
  unsigned x = __bfloat16_as_ushort(__float2bfloat16(a));
  unsigned y = __bfloat16_as_ushort(__float2bfloat16(b));
  return x | (y << 16);
}

// ---------------- dtype detect + constant prep + cursor zero (1 block) ----------------
__global__ void k_detect_prep(const unsigned short* __restrict__ raw, int* __restrict__ flag,
                              const void* al0, const void* ar0, const void* al1, const void* ar1,
                              const void* al2, const void* ar2, const void* b0, const void* b1,
                              const void* b2, float* __restrict__ att, int* __restrict__ cursor) {
  __shared__ int cnt[256];
  int t = threadIdx.x;
  for (int i = t; i < N_NODES; i += 256) cursor[i] = 0;   // replaces memset #1
  int c = 0;
  for (int i = t; i < 8192; i += 256) {
    int e = (raw[i] >> 7) & 0xFF;
    if (e >= 0x90) c++;
  }
  cnt[t] = c;
  __syncthreads();
  for (int s = 128; s; s >>= 1) {
    if (t < s) cnt[t] += cnt[t + s];
    __syncthreads();
  }
  __shared__ int sflag;
  if (t == 0) { sflag = (cnt[0] > 64) ? 0 : 1; *flag = sflag; }
  __syncthreads();
  int isbf = sflag;
  att[AT_AL0 + t] = ldflag(al0, t, isbf);
  att[AT_AR0 + t] = ldflag(ar0, t, isbf);
  att[AT_AL1 + t] = ldflag(al1, t, isbf);
  att[AT_AR1 + t] = ldflag(ar1, t, isbf);
  att[AT_B0 + t]  = ldflag(b0, t, isbf);
  att[AT_B1 + t]  = ldflag(b1, t, isbf);
  if (t < N_CLS) {
    att[AT_AL2 + t] = ldflag(al2, t, isbf);
    att[AT_AR2 + t] = ldflag(ar2, t, isbf);
    att[AT_B2 + t]  = ldflag(b2, t, isbf);
  }
}

// ---------------- CSR build (by dst) ----------------
__global__ void k_hist(const int* __restrict__ dst, int* __restrict__ cnt) {
  int e = blockIdx.x * blockDim.x + threadIdx.x;
  if (e < N_EDGES) atomicAdd(&cnt[dst[e]], 1);
}

#define SCAN_B 512
#define SCAN_NB ((N_NODES + SCAN_B - 1) / SCAN_B)   // 98

__global__ __launch_bounds__(SCAN_B) void k_scan_blocks(const int* __restrict__ deg,
                                                        int* __restrict__ excl,
                                                        int* __restrict__ partial) {
  __shared__ int buf[SCAN_B];
  int t = threadIdx.x;
  int i = blockIdx.x * SCAN_B + t;
  int v = (i < N_NODES) ? deg[i] : 0;
  buf[t] = v;
  __syncthreads();
  for (int off = 1; off < SCAN_B; off <<= 1) {
    int x = (t >= off) ? buf[t - off] : 0;
    __syncthreads();
    buf[t] += x;
    __syncthreads();
  }
  if (i < N_NODES) excl[i] = buf[t] - v;
  if (t == SCAN_B - 1) partial[blockIdx.x] = buf[t];
}

__global__ void k_scan_partials(int* __restrict__ partial, int* __restrict__ rowptr) {
  __shared__ int buf[SCAN_NB];
  int t = threadIdx.x;
  if (t < SCAN_NB) buf[t] = partial[t];
  __syncthreads();
  if (t == 0) {
    int run = 0;
    for (int b = 0; b < SCAN_NB; b++) { int v = buf[b]; buf[b] = run; run += v; }
    rowptr[N_NODES] = run;
  }
  __syncthreads();
  if (t < SCAN_NB) partial[t] = buf[t];
}

// adds partial sums AND re-zeros cursor for k_scatter (replaces memset #2)
__global__ void k_scan_add(int* __restrict__ rowptr, const int* __restrict__ partial,
                           int* __restrict__ cursor) {
  int i = blockIdx.x * blockDim.x + threadIdx.x;
  if (i < N_NODES) {
    rowptr[i] += partial[i / SCAN_B];
    cursor[i] = 0;
  }
}

__global__ void k_scatter(const int* __restrict__ src, const int* __restrict__ dst,
                          const int* __restrict__ rowptr, int* __restrict__ cursor,
                          int* __restrict__ csr_src) {
  int e = blockIdx.x * blockDim.x + threadIdx.x;
  if (e < N_EDGES) {
    int d = dst[e];
    int pos = rowptr[d] + atomicAdd(&cursor[d], 1);
    csr_src[pos] = src[e];
  }
}

// ---------------- all 3 weight transposes in one kernel -> bf16 [Ndst][K] ----------------
#define TW0 (HID * IN_F)            // 131072
#define TW1 (TW0 + HID * HID)       // 196608
#define TW2 (TW1 + NCLS_PAD * HID)  // 212992
__global__ void k_transpose_all(const void* __restrict__ W0, const void* __restrict__ W1,
                                const void* __restrict__ W2,
                                __hip_bfloat16* __restrict__ w0t, __hip_bfloat16* __restrict__ w1t,
                                __hip_bfloat16* __restrict__ w2t, const int* __restrict__ flag) {
  int isbf = *flag;
  int i = blockIdx.x * blockDim.x + threadIdx.x;
  if (i < TW0) {                       // w0t[256][512] <- W0[512][256]
    int n = i >> 9, k = i & 511;
    w0t[i] = __float2bfloat16(ldflag(W0, (long long)k * HID + n, isbf));
  } else if (i < TW1) {                // w1t[256][256] <- W1[256][256]
    int j = i - TW0;
    int n = j >> 8, k = j & 255;
    w1t[j] = __float2bfloat16(ldflag(W1, (long long)k * HID + n, isbf));
  } else if (i < TW2) {                // w2t[64][256] <- W2[256][40], pad cols 40..63
    int j = i - TW1;
    int n = j >> 8, k = j & 255;
    float v = (n < N_CLS) ? ldflag(W2, (long long)k * N_CLS + n, isbf) : 0.f;
    w2t[j] = __float2bfloat16(v);
  }
}

// ---------------- A/B staging loads (dual-dtype A: cast fused) ----------------
__device__ __forceinline__ uint4 loadA(const void* A, int isbf, int ga, int M, int K, int off) {
  uint4 av = make_uint4(0u, 0u, 0u, 0u);
  if (ga < M) {
    if (isbf) {
      av = *(const uint4*)((const __hip_bfloat16*)A + (size_t)ga * K + off);
    } else {
      const float* ap = (const float*)A + (size_t)ga * K + off;
      float4 f1 = *(const float4*)ap;
      float4 f2 = *(const float4*)(ap + 4);
      av.x = pk2(f1.x, f1.y); av.y = pk2(f1.z, f1.w);
      av.z = pk2(f2.x, f2.y); av.w = pk2(f2.z, f2.w);
    }
  }
  return av;
}

// ---------------- MFMA bf16 GEMM, 64x64 tile, XCD-swizzled, prefetch-pipelined ----------------
// C[M][N] = A[M][K] * Bt[N][K]^T. Register double-buffer: k+1's A/B global loads are
// issued BEFORE tile k's MFMA section, so their latency hides behind MFMA + ds_reads
// (round-7 analysis: the synchronous load->barrier chain exposed ~600-900 cyc x K/32 per
// block). Swizzle: blocks sharing an A-tile sit at ids {j,j+8,j+16,j+24} -> same XCD.
// If fuse_eler: each wave's acc quadrant covers exactly one head's 32 cols ->
// el/er computed in-epilogue (2 FMAs/row/lane + 16-lane butterfly), no eler kernel.
__global__ __launch_bounds__(256) void k_gemm64(const void* __restrict__ A,
                                                const __hip_bfloat16* __restrict__ Bt,
                                                __hip_bfloat16* __restrict__ C,
                                                int M, int K, int N,
                                                const int* __restrict__ flag, int force_bf,
                                                const float* __restrict__ al,
                                                const float* __restrict__ ar,
                                                float* __restrict__ el,
                                                float* __restrict__ er, int fuse_eler) {
  __shared__ unsigned short As[64][40];  // 80 B pitch: 16B-aligned rows, spreads banks
  __shared__ unsigned short Bs[64][40];
  const int isbf = force_bf ? 1 : *flag;
  int nblk = N >> 6;
  int per = nblk << 3;                 // blocks per group
  int g = blockIdx.x / per;
  int i2 = blockIdx.x - g * per;
  int mb = g * 8 + (i2 & 7);
  int nb = i2 >> 3;
  int m0 = mb * 64, n0 = nb * 64;
  if (m0 >= M) return;
  int tid = threadIdx.x;
  int lrow = tid >> 2;          // 0..63
  int lcol = (tid & 3) * 8;     // 0,8,16,24
  int wave = tid >> 6, lane = tid & 63;
  int wm = (wave >> 1) * 32, wn = (wave & 1) * 32;
  int lm = lane & 15, quad = lane >> 4;
  f32x4 acc[2][2] = {};
  // prologue load for k0 = 0
  uint4 av = loadA(A, isbf, m0 + lrow, M, K, lcol);
  uint4 bv = *(const uint4*)(Bt + (size_t)(n0 + lrow) * K + lcol);
  for (int k0 = 0; k0 < K; k0 += 32) {
    __syncthreads();            // previous iteration's LDS reads done
    *(uint4*)(&As[lrow][lcol]) = av;
    *(uint4*)(&Bs[lrow][lcol]) = bv;
    __syncthreads();
    // issue k+1's loads now; they drain behind the MFMA section below
    uint4 avn = make_uint4(0u, 0u, 0u, 0u), bvn = make_uint4(0u, 0u, 0u, 0u);
    if (k0 + 32 < K) {
      avn = loadA(A, isbf, m0 + lrow, M, K, k0 + 32 + lcol);
      bvn = *(const uint4*)(Bt + (size_t)(n0 + lrow) * K + k0 + 32 + lcol);
    }
    bf16x8 af[2], bfr[2];
    #pragma unroll
    for (int i = 0; i < 2; i++) {
      af[i]  = *(const bf16x8*)(&As[wm + i * 16 + lm][quad * 8]);
      bfr[i] = *(const bf16x8*)(&Bs[wn + i * 16 + lm][quad * 8]);
    }
    #pragma unroll
    for (int mi = 0; mi < 2; mi++)
      #pragma unroll
      for (int ni = 0; ni < 2; ni++)
        acc[mi][ni] = __builtin_amdgcn_mfma_f32_16x16x32_bf16(af[mi], bfr[ni], acc[mi][ni], 0, 0, 0);
    av = avn; bv = bvn;
  }
  // C/D layout: col = lane&15, row = quad*4 + r  (m89/m91 verified)
  #pragma unroll
  for (int mi = 0; mi < 2; mi++)
    #pragma unroll
    for (int ni = 0; ni < 2; ni++)
      #pragma unroll
      for (int r = 0; r < 4; r++) {
        int gm = m0 + wm + mi * 16 + quad * 4 + r;
        int gn = n0 + wn + ni * 16 + lm;
        if (gm < M) C[(size_t)gm * N + gn] = __float2bfloat16(acc[mi][ni][r]);
      }
  if (fuse_eler) {
    // this wave's cols n0+wn .. n0+wn+31 = exactly head hg (wn in {0,32}, n0 % 64 == 0)
    int hg = (n0 + wn) >> 5;
    float ala[2], ara[2];
    #pragma unroll
    for (int ni = 0; ni < 2; ni++) {
      ala[ni] = al[hg * DHEAD + ni * 16 + lm];
      ara[ni] = ar[hg * DHEAD + ni * 16 + lm];
    }
    #pragma unroll
    for (int mi = 0; mi < 2; mi++)
      #pragma unroll
      for (int r = 0; r < 4; r++) {
        float pl = acc[mi][0][r] * ala[0] + acc[mi][1][r] * ala[1];
        float pr = acc[mi][0][r] * ara[0] + acc[mi][1][r] * ara[1];
        #pragma unroll
        for (int d = 1; d < 16; d <<= 1) {   // butterfly over the 16 lm lanes (same quad)
          pl += __shfl_xor(pl, d, 16);
          pr += __shfl_xor(pr, d, 16);
        }
        int gm = m0 + wm + mi * 16 + quad * 4 + r;
        if (lm == 0 && gm < M) {
          el[gm * HEADS + hg] = pl;
          er[gm * HEADS + hg] = pr;
        }
      }
  }
}

// ---------------- el/er for layer 2 (1 head, 40 dims, stride 64) ----------------
__global__ void k_eler2(const __hip_bfloat16* __restrict__ feat2,
                        const float* __restrict__ al, const float* __restrict__ ar,
                        float* __restrict__ el, float* __restrict__ er) {
  int n = blockIdx.x * blockDim.x + threadIdx.x;
  if (n >= N_NODES) return;
  const __hip_bfloat16* f = feat2 + (size_t)n * NCLS_PAD;
  float sl = 0.f, sr = 0.f;
  for (int d = 0; d < N_CLS; d++) {
    float v = __bfloat162float(f[d]);
    sl += v * al[d];
    sr += v * ar[d];
  }
  el[n] = sl;
  er[n] = sr;
}

// ---------------- fused edge-softmax + aggregation, 8 slots x 32 lanes ----------------
// lane owns 8 channels (uint4/edge). No max-subtraction (shift-invariant, exp clamped).
// Unroll-2: two independent csr->el/feat gather chains in flight (latency-bound fix).
__global__ __launch_bounds__(256) void k_aggregate8(const int* __restrict__ rowptr,
                                                    const int* __restrict__ csr_src,
                                                    const uint4* __restrict__ feat_rows,
                                                    const float* __restrict__ el,
                                                    const float* __restrict__ er,
                                                    const float* __restrict__ bias,
                                                    __hip_bfloat16* __restrict__ out) {
  __shared__ float lds_acc[8][256];
  __shared__ float lds_l[8][32];
  int n = blockIdx.x;
  int t = threadIdx.x;
  int slot = t >> 5;      // 0..7
  int c = t & 31;         // channel group: channels c*8..c*8+7
  int hh = c >> 2;        // head of this group
  float er_n = er[n * HEADS + hh];
  int beg = rowptr[n], end = rowptr[n + 1];
  float l = 0.f;
  float acc[8] = {0.f, 0.f, 0.f, 0.f, 0.f, 0.f, 0.f, 0.f};
  int i = beg + slot;
  for (; i + 8 < end; i += 16) {
    int s1 = csr_src[i];
    int s2 = csr_src[i + 8];
    float el1 = el[s1 * HEADS + hh];
    float el2 = el[s2 * HEADS + hh];
    uint4 f1 = feat_rows[(size_t)s1 * 32 + c];
    uint4 f2 = feat_rows[(size_t)s2 * 32 + c];
    float x1 = el1 + er_n, x2 = el2 + er_n;
    float e1 = x1 > 0.f ? x1 : 0.2f * x1;
    float e2 = x2 > 0.f ? x2 : 0.2f * x2;
    float p1 = __expf(fminf(e1, 60.f));
    float p2 = __expf(fminf(e2, 60.f));
    l += p1 + p2;
    acc[0] += p1 * blo(f1.x) + p2 * blo(f2.x); acc[1] += p1 * bhi(f1.x) + p2 * bhi(f2.x);
    acc[2] += p1 * blo(f1.y) + p2 * blo(f2.y); acc[3] += p1 * bhi(f1.y) + p2 * bhi(f2.y);
    acc[4] += p1 * blo(f1.z) + p2 * blo(f2.z); acc[5] += p1 * bhi(f1.z) + p2 * bhi(f2.z);
    acc[6] += p1 * blo(f1.w) + p2 * blo(f2.w); acc[7] += p1 * bhi(f1.w) + p2 * bhi(f2.w);
  }
  if (i < end) {
    int s = csr_src[i];
    float elv = el[s * HEADS + hh];
    uint4 fv = feat_rows[(size_t)s * 32 + c];
    float x = elv + er_n;
    float e = x > 0.f ? x : 0.2f * x;
    float p = __expf(fminf(e, 60.f));
    l += p;
    acc[0] += p * blo(fv.x); acc[1] += p * bhi(fv.x);
    acc[2] += p * blo(fv.y); acc[3] += p * bhi(fv.y);
    acc[4] += p * blo(fv.z); acc[5] += p * bhi(fv.z);
    acc[6] += p * blo(fv.w); acc[7] += p * bhi(fv.w);
  }
  *(float4*)&lds_acc[slot][c * 8]     = make_float4(acc[0], acc[1], acc[2], acc[3]);
  *(float4*)&lds_acc[slot][c * 8 + 4] = make_float4(acc[4], acc[5], acc[6], acc[7]);
  lds_l[slot][c] = l;
  __syncthreads();
  float a = 0.f, L = 0.f;
  #pragma unroll
  for (int s2 = 0; s2 < 8; s2++) { a += lds_acc[s2][t]; L += lds_l[s2][t >> 3]; }
  float o = a / fmaxf(L, 1e-9f) + bias[t];
  o = fmaxf(o, 0.f);                            // ReLU (layers 0,1)
  out[(size_t)n * HID + t] = __float2bfloat16(o);
}

// ---------------- layer 2 aggregate: 32 slots x 8 lanes (64-ch padded rows) ----------------
__global__ __launch_bounds__(256) void k_aggregate1(const int* __restrict__ rowptr,
                                                    const int* __restrict__ csr_src,
                                                    const uint4* __restrict__ fr2,  // [N][8] uint4
                                                    const float* __restrict__ el,
                                                    const float* __restrict__ er,
                                                    const float* __restrict__ bias,
                                                    void* __restrict__ out,
                                                    const int* __restrict__ flag) {
  __shared__ float lds_acc[32][64];
  __shared__ float lds_l[32][8];
  int isbf = *flag;
  int n = blockIdx.x;
  int t = threadIdx.x;
  int slot = t >> 3;      // 0..31
  int c = t & 7;
  float er_n = er[n];
  int beg = rowptr[n], end = rowptr[n + 1];
  float l = 0.f;
  float acc[8] = {0.f, 0.f, 0.f, 0.f, 0.f, 0.f, 0.f, 0.f};
  int i = beg + slot;
  for (; i + 32 < end; i += 64) {
    int s1 = csr_src[i], s2 = csr_src[i + 32];
    float el1 = el[s1], el2 = el[s2];
    uint4 f1 = fr2[(size_t)s1 * 8 + c];
    uint4 f2 = fr2[(size_t)s2 * 8 + c];
    float x1 = el1 + er_n, x2 = el2 + er_n;
    float e1 = x1 > 0.f ? x1 : 0.2f * x1;
    float e2 = x2 > 0.f ? x2 : 0.2f * x2;
    float p1 = __expf(fminf(e1, 60.f));
    float p2 = __expf(fminf(e2, 60.f));
    l += p1 + p2;
    acc[0] += p1 * blo(f1.x) + p2 * blo(f2.x); acc[1] += p1 * bhi(f1.x) + p2 * bhi(f2.x);
    acc[2] += p1 * blo(f1.y) + p2 * blo(f2.y); acc[3] += p1 * bhi(f1.y) + p2 * bhi(f2.y);
    acc[4] += p1 * blo(f1.z) + p2 * blo(f2.z); acc[5] += p1 * bhi(f1.z) + p2 * bhi(f2.z);
    acc[6] += p1 * blo(f1.w) + p2 * blo(f2.w); acc[7] += p1 * bhi(f1.w) + p2 * bhi(f2.w);
  }
  if (i < end) {
    int s = csr_src[i];
    float x = el[s] + er_n;
    uint4 fv = fr2[(size_t)s * 8 + c];
    float e = x > 0.f ? x : 0.2f * x;
    float p = __expf(fminf(e, 60.f));
    l += p;
    acc[0] += p * blo(fv.x); acc[1] += p * bhi(fv.x);
    acc[2] += p * blo(fv.y); acc[3] += p * bhi(fv.y);
    acc[4] += p * blo(fv.z); acc[5] += p * bhi(fv.z);
    acc[6] += p * blo(fv.w); acc[7] += p * bhi(fv.w);
  }
  *(float4*)&lds_acc[slot][c * 8]     = make_float4(acc[0], acc[1], acc[2], acc[3]);
  *(float4*)&lds_acc[slot][c * 8 + 4] = make_float4(acc[4], acc[5], acc[6], acc[7]);
  lds_l[slot][c] = l;
  __syncthreads();
  if (t < N_CLS) {
    float a = 0.f, L = 0.f;
    #pragma unroll
    for (int s2 = 0; s2 < 32; s2++) { a += lds_acc[s2][t]; L += lds_l[s2][t >> 3]; }
    float o = a / fmaxf(L, 1e-9f) + bias[t];    // no ReLU on output layer
    if (isbf) ((__hip_bfloat16*)out)[(size_t)n * N_CLS + t] = __float2bfloat16(o);
    else      ((float*)out)[(size_t)n * N_CLS + t] = o;
  }
}

// ---------------- launch ----------------
static inline size_t align_up(size_t x) { return (x + 255) & ~(size_t)255; }

extern "C" void kernel_launch(void* const* d_in, const int* in_sizes, int n_in,
                              void* d_out, int out_size, void* d_ws, size_t ws_size,
                              hipStream_t stream) {
  const void* in_feat = d_in[0];
  const int* src = (const int*)d_in[1];
  const int* dst = (const int*)d_in[2];
  const void* W0  = d_in[3];
  const void* al0 = d_in[4];
  const void* ar0 = d_in[5];
  const void* b0  = d_in[6];
  const void* W1  = d_in[7];
  const void* al1 = d_in[8];
  const void* ar1 = d_in[9];
  const void* b1  = d_in[10];
  const void* W2  = d_in[11];
  const void* al2 = d_in[12];
  const void* ar2 = d_in[13];
  const void* b2  = d_in[14];

  char* p = (char*)d_ws;
  int* flag = (int*)p;                   p += 256;
  float* att = (float*)p;                p += align_up(AT_SZ * sizeof(float));
  int* rowptr = (int*)p;                 p += align_up((N_NODES + 1) * sizeof(int));
  int* cursor = (int*)p;                 p += align_up(N_NODES * sizeof(int));
  int* csr_src = (int*)p;                p += align_up(N_EDGES * sizeof(int));
  int* partial = (int*)p;                p += align_up(SCAN_NB * sizeof(int));
  __hip_bfloat16* feat16 = (__hip_bfloat16*)p; p += align_up((size_t)N_NODES * HID * sizeof(__hip_bfloat16));
  __hip_bfloat16* h16 = (__hip_bfloat16*)p;    p += align_up((size_t)N_NODES * HID * sizeof(__hip_bfloat16));
  float* el = (float*)p;                 p += align_up((size_t)N_NODES * HEADS * sizeof(float));
  float* er = (float*)p;                 p += align_up((size_t)N_NODES * HEADS * sizeof(float));
  __hip_bfloat16* w0t = (__hip_bfloat16*)p;    p += align_up((size_t)HID * IN_F * sizeof(__hip_bfloat16));
  __hip_bfloat16* w1t = (__hip_bfloat16*)p;    p += align_up((size_t)HID * HID * sizeof(__hip_bfloat16));
  __hip_bfloat16* w2t = (__hip_bfloat16*)p;    p += align_up((size_t)NCLS_PAD * HID * sizeof(__hip_bfloat16));

  const int EB = (N_EDGES + 255) / 256;
  const int MB64 = (N_NODES + 63) / 64;          // 782
  const int GROUPS = (MB64 + 7) / 8;             // 98
  const int G4 = GROUPS * 8 * 4;                 // swizzled grid, nblk=4 (3136)
  const int G1 = GROUPS * 8 * 1;                 // swizzled grid, nblk=1 (784)

  // ---- dtype detection + constant prep + cursor zero ----
  k_detect_prep<<<1, 256, 0, stream>>>((const unsigned short*)in_feat, flag,
                                       al0, ar0, al1, ar1, al2, ar2, b0, b1, b2, att, cursor);

  // ---- CSR build ----
  k_hist<<<EB, 256, 0, stream>>>(dst, cursor);
  k_scan_blocks<<<SCAN_NB, SCAN_B, 0, stream>>>(cursor, rowptr, partial);
  k_scan_partials<<<1, 128, 0, stream>>>(partial, rowptr);
  k_scan_add<<<(N_NODES + 255) / 256, 256, 0, stream>>>(rowptr, partial, cursor);
  k_scatter<<<EB, 256, 0, stream>>>(src, dst, rowptr, cursor, csr_src);

  // ---- weight transposes (merged, -> bf16 [N][K]) ----
  k_transpose_all<<<(TW2 + 255) / 256, 256, 0, stream>>>(W0, W1, W2, w0t, w1t, w2t, flag);

  // ---- layer 0 (cast + el/er fused into GEMM) ----
  k_gemm64<<<G4, 256, 0, stream>>>(in_feat, w0t, feat16, N_NODES, IN_F, HID, flag, 0,
                                   att + AT_AL0, att + AT_AR0, el, er, 1);
  k_aggregate8<<<N_NODES, 256, 0, stream>>>(rowptr, csr_src, (const uint4*)feat16, el, er, att + AT_B0, h16);

  // ---- layer 1 ----
  k_gemm64<<<G4, 256, 0, stream>>>(h16, w1t, feat16, N_NODES, HID, HID, flag, 1,
                                   att + AT_AL1, att + AT_AR1, el, er, 1);
  k_aggregate8<<<N_NODES, 256, 0, stream>>>(rowptr, csr_src, (const uint4*)feat16, el, er, att + AT_B1, h16);

  // ---- layer 2 (feat16 reused as [N][64] padded feat2) ----
  k_gemm64<<<G1, 256, 0, stream>>>(h16, w2t, feat16, N_NODES, HID, NCLS_PAD, flag, 1,
                                   nullptr, nullptr, nullptr, nullptr, 0);
  k_eler2<<<(N_NODES + 255) / 256, 256, 0, stream>>>(feat16, att + AT_AL2, att + AT_AR2, el, er);
  k_aggregate1<<<N_NODES, 256, 0, stream>>>(rowptr, csr_src, (const uint4*)feat16, el, er, att + AT_B2, d_out, flag);
}